// Round 1
// baseline (19041.216 us; speedup 1.0000x reference)
//
#include <hip/hip_runtime.h>
#include <hip/hip_bf16.h>
#include <math.h>

// ---- problem dims ----
#define B_    8
#define T_    256
#define S_    16
#define H_    1024
#define NH_   16
#define L_    6
#define NI_   4096
#define TIME_ 8
#define T3_   768           // 3*T
#define DH_   64            // H/NH
#define BT_   2048          // B*T
#define ROWS_ 6144          // B*T3
#define KE_   1032          // H + TIME
#define NEGV  (-10000.0f)

// =====================================================================
// K1: embedding pre-stage: te gather + tiny-K projections into U buffers
//     U_x rows are 1032 wide: [proj(1024), te(8)] so stage-2 is a plain GEMM
// =====================================================================
__global__ __launch_bounds__(256) void embed_pre_kernel(
    const float* __restrict__ states, const float* __restrict__ actions,
    const float* __restrict__ rtgs, const float* __restrict__ mean,
    const float* __restrict__ stdv, const float* __restrict__ W_es,
    const float* __restrict__ b_es, const float* __restrict__ W_ea,
    const float* __restrict__ b_ea, const float* __restrict__ W_er,
    const float* __restrict__ b_er, const float* __restrict__ E_t,
    const int* __restrict__ timesteps,
    float* __restrict__ Us, float* __restrict__ Ua, float* __restrict__ Ur)
{
    const int bt  = blockIdx.x;      // 0..2047
    const int tid = threadIdx.x;
    __shared__ float sn[S_];
    __shared__ float tev[TIME_];
    if (tid < S_) sn[tid] = (states[bt * S_ + tid] - mean[tid]) / (stdv[tid] + 1e-9f);
    if (tid < TIME_) {
        int ts = timesteps[bt];
        tev[tid] = E_t[ts * TIME_ + tid];
    }
    __syncthreads();
    const float av = actions[bt];   // A == 1
    const float rv = rtgs[bt];
    #pragma unroll
    for (int u = 0; u < 4; ++u) {
        int n = tid + u * 256;
        float accs = b_es[n];
        #pragma unroll
        for (int i = 0; i < S_; ++i) accs += sn[i] * W_es[i * H_ + n];
        Us[(size_t)bt * KE_ + n] = accs;
        Ua[(size_t)bt * KE_ + n] = av * W_ea[n] + b_ea[n];
        Ur[(size_t)bt * KE_ + n] = rv * W_er[n] + b_er[n];
    }
    if (tid < TIME_) {
        float tv = tev[tid];
        Us[(size_t)bt * KE_ + H_ + tid] = tv;
        Ua[(size_t)bt * KE_ + H_ + tid] = tv;
        Ur[(size_t)bt * KE_ + H_ + tid] = tv;
    }
}

// =====================================================================
// Generic fp32 tiled GEMM: C(M,N) = A(M,K) @ W(K,N) + bias  [+epilogue]
// EPI: 0 = bias only, 1 = bias + add existing C (residual), 2 = bias + exact gelu
// BM=BN=64, BK=16, 256 threads, 4x4 micro-tile per thread.
// =====================================================================
__device__ __forceinline__ float gelu_exact(float x) {
    return x * 0.5f * (1.0f + erff(x * 0.70710678118654752f));
}

template <int EPI>
__global__ __launch_bounds__(256) void gemm_kernel(
    const float* __restrict__ A, const float* __restrict__ W,
    const float* __restrict__ bias, float* __restrict__ C,
    int M, int N, int K, int lda)
{
    __shared__ float As[16][68];  // As[k][m]
    __shared__ float Ws[16][68];  // Ws[k][n]
    const int tid = threadIdx.x;
    const int tx = tid & 15, ty = tid >> 4;
    const int bm = blockIdx.y * 64, bn = blockIdx.x * 64;
    float acc[4][4] = {};
    for (int k0 = 0; k0 < K; k0 += 16) {
        // load A tile 64x16 (4 consecutive k-cols per thread)
        const int e = tid * 4;
        const int ar = e >> 4, ac0 = e & 15;
        const float* Arow = A + (size_t)(bm + ar) * lda + k0 + ac0;
        #pragma unroll
        for (int u = 0; u < 4; ++u) {
            int kk = k0 + ac0 + u;
            As[ac0 + u][ar] = (kk < K) ? Arow[u] : 0.0f;
        }
        // load W tile 16x64
        const int wr = tid >> 4, wc = (tid & 15) * 4;
        const float* Wrow = W + (size_t)(k0 + wr) * N + bn + wc;
        const bool wok = (k0 + wr) < K;
        #pragma unroll
        for (int u = 0; u < 4; ++u)
            Ws[wr][wc + u] = wok ? Wrow[u] : 0.0f;
        __syncthreads();
        #pragma unroll
        for (int i = 0; i < 16; ++i) {
            float a[4], w[4];
            #pragma unroll
            for (int j = 0; j < 4; ++j) a[j] = As[i][ty * 4 + j];
            #pragma unroll
            for (int j = 0; j < 4; ++j) w[j] = Ws[i][tx * 4 + j];
            #pragma unroll
            for (int jj = 0; jj < 4; ++jj)
                #pragma unroll
                for (int kk = 0; kk < 4; ++kk)
                    acc[jj][kk] += a[jj] * w[kk];
        }
        __syncthreads();
    }
    #pragma unroll
    for (int jj = 0; jj < 4; ++jj) {
        const int row = bm + ty * 4 + jj;
        #pragma unroll
        for (int kk = 0; kk < 4; ++kk) {
            const int col = bn + tx * 4 + kk;
            float v = acc[jj][kk] + bias[col];
            if (EPI == 2) v = gelu_exact(v);
            const size_t idx = (size_t)row * N + col;
            if (EPI == 1) v += C[idx];
            C[idx] = v;
        }
    }
}

// =====================================================================
// LayerNorm over rows of 1024 (eps 1e-5), y = (x-m)*rsqrt(v+eps)*g + b
// =====================================================================
__device__ __forceinline__ void ln_body(const float* __restrict__ src,
                                        const float* __restrict__ g,
                                        const float* __restrict__ b,
                                        float* __restrict__ dst,
                                        float* red, int tid)
{
    float v[4];
    #pragma unroll
    for (int u = 0; u < 4; ++u) v[u] = src[tid + u * 256];
    float s = v[0] + v[1] + v[2] + v[3];
    red[tid] = s; __syncthreads();
    for (int off = 128; off > 0; off >>= 1) {
        if (tid < off) red[tid] += red[tid + off];
        __syncthreads();
    }
    const float mean = red[0] * (1.0f / H_);
    __syncthreads();
    float ss = 0.0f;
    #pragma unroll
    for (int u = 0; u < 4; ++u) { float d = v[u] - mean; ss += d * d; }
    red[tid] = ss; __syncthreads();
    for (int off = 128; off > 0; off >>= 1) {
        if (tid < off) red[tid] += red[tid + off];
        __syncthreads();
    }
    const float var = red[0] * (1.0f / H_);
    const float rs = rsqrtf(var + 1e-5f);
    #pragma unroll
    for (int u = 0; u < 4; ++u) {
        int col = tid + u * 256;
        dst[col] = (v[u] - mean) * rs * g[col] + b[col];
    }
}

__global__ __launch_bounds__(256) void ln_kernel(
    const float* __restrict__ X, const float* __restrict__ g,
    const float* __restrict__ b, float* __restrict__ Y)
{
    __shared__ float red[256];
    const size_t row = blockIdx.x;
    ln_body(X + row * H_, g, b, Y + row * H_, red, threadIdx.x);
}

// K3: gather re/se/ae interleaved + embedding LN, writes X
__global__ __launch_bounds__(256) void interleave_eln_kernel(
    const float* __restrict__ RE, const float* __restrict__ SE,
    const float* __restrict__ AE, const float* __restrict__ g,
    const float* __restrict__ b, float* __restrict__ X)
{
    __shared__ float red[256];
    const int row = blockIdx.x;           // 0..6143
    const int bi = row / T3_;
    const int rem = row % T3_;
    const int t = rem / 3, slot = rem % 3;
    const float* src = (slot == 0 ? RE : (slot == 1 ? SE : AE)) + (size_t)(bi * T_ + t) * H_;
    ln_body(src, g, b, X + (size_t)row * H_, red, threadIdx.x);
}

// =====================================================================
// K6: flash-style causal attention, fp32.
// One block per (q-tile of 64, head, batch). 256 threads, 4x4 micro-tiles.
// =====================================================================
__global__ __launch_bounds__(256) void attn_kernel(
    const float* __restrict__ Q, const float* __restrict__ K,
    const float* __restrict__ V, const float* __restrict__ amask,
    float* __restrict__ Y)
{
    const int qt = blockIdx.x;   // 0..11
    const int h  = blockIdx.y;   // 0..15
    const int b  = blockIdx.z;   // 0..7
    const int tid = threadIdx.x;
    const int tx = tid & 15, ty = tid >> 4;
    const int r0 = ty * 4, c0 = tx * 4;

    __shared__ float qs[64][65];
    __shared__ float kps[64][65];   // K tile, reused as P tile after scores read
    __shared__ float vs[64][65];
    __shared__ float red[64][17];
    __shared__ float padv[64];

    const size_t base = ((size_t)b * T3_) * H_ + (size_t)h * DH_;

    #pragma unroll
    for (int c = 0; c < 16; ++c) {
        int idx = c * 256 + tid;
        int rr = idx >> 6, cc = idx & 63;
        qs[rr][cc] = Q[base + (size_t)(qt * 64 + rr) * H_ + cc];
    }

    float m_i[4], l_i[4], o[4][4];
    #pragma unroll
    for (int j = 0; j < 4; ++j) {
        m_i[j] = -3.0e30f; l_i[j] = 0.0f;
        #pragma unroll
        for (int k = 0; k < 4; ++k) o[j][k] = 0.0f;
    }

    for (int kt = 0; kt <= qt; ++kt) {
        #pragma unroll
        for (int c = 0; c < 16; ++c) {
            int idx = c * 256 + tid;
            int rr = idx >> 6, cc = idx & 63;
            kps[rr][cc] = K[base + (size_t)(kt * 64 + rr) * H_ + cc];
            vs[rr][cc]  = V[base + (size_t)(kt * 64 + rr) * H_ + cc];
        }
        if (tid < 64) {
            int j = kt * 64 + tid;
            padv[tid] = (1.0f - amask[b * T_ + j / 3]) * NEGV;
        }
        __syncthreads();

        // scores S = Q K^T
        float s[4][4];
        #pragma unroll
        for (int jj = 0; jj < 4; ++jj)
            #pragma unroll
            for (int kk = 0; kk < 4; ++kk) s[jj][kk] = 0.0f;
        for (int i = 0; i < 64; ++i) {
            float a[4], w[4];
            #pragma unroll
            for (int j = 0; j < 4; ++j) a[j] = qs[r0 + j][i];
            #pragma unroll
            for (int j = 0; j < 4; ++j) w[j] = kps[c0 + j][i];
            #pragma unroll
            for (int jj = 0; jj < 4; ++jj)
                #pragma unroll
                for (int kk = 0; kk < 4; ++kk)
                    s[jj][kk] += a[jj] * w[kk];
        }
        // scale + causal + pad, thread-local row max
        float tmax[4];
        #pragma unroll
        for (int jj = 0; jj < 4; ++jj) {
            const int qr = qt * 64 + r0 + jj;
            tmax[jj] = -3.0e30f;
            #pragma unroll
            for (int kk = 0; kk < 4; ++kk) {
                const int jc = kt * 64 + c0 + kk;
                float val = (jc <= qr) ? s[jj][kk] * 0.125f : NEGV;
                val += padv[c0 + kk];
                s[jj][kk] = val;
                tmax[jj] = fmaxf(tmax[jj], val);
            }
        }
        #pragma unroll
        for (int jj = 0; jj < 4; ++jj) red[r0 + jj][tx] = tmax[jj];
        __syncthreads();
        float mnew[4], alpha[4];
        #pragma unroll
        for (int jj = 0; jj < 4; ++jj) {
            float rm = -3.0e30f;
            #pragma unroll
            for (int x = 0; x < 16; ++x) rm = fmaxf(rm, red[r0 + jj][x]);
            mnew[jj] = fmaxf(m_i[jj], rm);
            alpha[jj] = expf(m_i[jj] - mnew[jj]);
        }
        __syncthreads();   // red reads done before reuse; kps reads done before P write
        float rsum[4];
        #pragma unroll
        for (int jj = 0; jj < 4; ++jj) {
            float sm = 0.0f;
            #pragma unroll
            for (int kk = 0; kk < 4; ++kk) {
                float p = expf(s[jj][kk] - mnew[jj]);
                s[jj][kk] = p; sm += p;
            }
            rsum[jj] = sm;
        }
        #pragma unroll
        for (int jj = 0; jj < 4; ++jj) red[r0 + jj][tx] = rsum[jj];
        #pragma unroll
        for (int jj = 0; jj < 4; ++jj)
            #pragma unroll
            for (int kk = 0; kk < 4; ++kk)
                kps[r0 + jj][c0 + kk] = s[jj][kk];   // P tile
        __syncthreads();
        #pragma unroll
        for (int jj = 0; jj < 4; ++jj) {
            float tot = 0.0f;
            #pragma unroll
            for (int x = 0; x < 16; ++x) tot += red[r0 + jj][x];
            l_i[jj] = l_i[jj] * alpha[jj] + tot;
            m_i[jj] = mnew[jj];
        }
        // O = O*alpha + P @ V
        #pragma unroll
        for (int jj = 0; jj < 4; ++jj)
            #pragma unroll
            for (int kk = 0; kk < 4; ++kk) o[jj][kk] *= alpha[jj];
        for (int c = 0; c < 64; ++c) {
            float pv[4], vv[4];
            #pragma unroll
            for (int jj = 0; jj < 4; ++jj) pv[jj] = kps[r0 + jj][c];
            #pragma unroll
            for (int kk = 0; kk < 4; ++kk) vv[kk] = vs[c][c0 + kk];
            #pragma unroll
            for (int jj = 0; jj < 4; ++jj)
                #pragma unroll
                for (int kk = 0; kk < 4; ++kk)
                    o[jj][kk] += pv[jj] * vv[kk];
        }
        __syncthreads();   // before next tile overwrites kps/vs
    }
    #pragma unroll
    for (int jj = 0; jj < 4; ++jj) {
        const int qr = qt * 64 + r0 + jj;
        const float inv = 1.0f / l_i[jj];
        #pragma unroll
        for (int kk = 0; kk < 4; ++kk)
            Y[base + (size_t)qr * H_ + c0 + kk] = o[jj][kk] * inv;
    }
}

// =====================================================================
// K7: action head — out[b,t] = dot(X[b, 3t+1, :], W_pa) + b_pa
// =====================================================================
__global__ __launch_bounds__(256) void head_kernel(
    const float* __restrict__ X, const float* __restrict__ W_pa,
    const float* __restrict__ b_pa, float* __restrict__ out)
{
    __shared__ float red[256];
    const int row = blockIdx.x;              // 0..2047
    const int b = row / T_, t = row % T_;
    const float* x = X + ((size_t)b * T3_ + 3 * t + 1) * H_;
    const int tid = threadIdx.x;
    float s = 0.0f;
    #pragma unroll
    for (int u = 0; u < 4; ++u) {
        int col = tid + u * 256;
        s += x[col] * W_pa[col];
    }
    red[tid] = s; __syncthreads();
    for (int off = 128; off > 0; off >>= 1) {
        if (tid < off) red[tid] += red[tid + off];
        __syncthreads();
    }
    if (tid == 0) out[row] = red[0] + b_pa[0];
}

// =====================================================================
extern "C" void kernel_launch(void* const* d_in, const int* in_sizes, int n_in,
                              void* d_out, int out_size, void* d_ws, size_t ws_size,
                              hipStream_t stream)
{
    const float* states  = (const float*)d_in[0];
    const float* actions = (const float*)d_in[1];
    const float* rtgs    = (const float*)d_in[2];
    const float* amask   = (const float*)d_in[3];
    const float* smean   = (const float*)d_in[4];
    const float* sstd    = (const float*)d_in[5];
    const float* W_es    = (const float*)d_in[6];
    const float* b_es    = (const float*)d_in[7];
    const float* W_ea    = (const float*)d_in[8];
    const float* b_ea    = (const float*)d_in[9];
    const float* W_er    = (const float*)d_in[10];
    const float* b_er    = (const float*)d_in[11];
    const float* E_t     = (const float*)d_in[12];
    const float* W_ts    = (const float*)d_in[13];
    const float* b_ts    = (const float*)d_in[14];
    const float* W_ta    = (const float*)d_in[15];
    const float* b_ta    = (const float*)d_in[16];
    const float* W_tr    = (const float*)d_in[17];
    const float* b_tr    = (const float*)d_in[18];
    const float* eln_g   = (const float*)d_in[19];
    const float* eln_b   = (const float*)d_in[20];
    const float* ln1_g   = (const float*)d_in[21];
    const float* ln1_b   = (const float*)d_in[22];
    const float* ln2_g   = (const float*)d_in[23];
    const float* ln2_b   = (const float*)d_in[24];
    const float* Wq      = (const float*)d_in[25];
    const float* bq      = (const float*)d_in[26];
    const float* Wk      = (const float*)d_in[27];
    const float* bk      = (const float*)d_in[28];
    const float* Wv      = (const float*)d_in[29];
    const float* bv      = (const float*)d_in[30];
    const float* Wo      = (const float*)d_in[31];
    const float* bo      = (const float*)d_in[32];
    const float* W1      = (const float*)d_in[33];
    const float* b1      = (const float*)d_in[34];
    const float* W2      = (const float*)d_in[35];
    const float* b2      = (const float*)d_in[36];
    const float* W_pa    = (const float*)d_in[37];
    const float* b_pa    = (const float*)d_in[38];
    const int*   tsteps  = (const int*)d_in[39];
    float* out = (float*)d_out;

    // ---- workspace layout (floats) ----
    // X:   ROWS_*H_                                   (residual stream)
    // RB:  4*ROWS_*H_ == ROWS_*NI_  (h/q/k/v during attn; MID during MLP;
    //                                U_s/U_a/U_r during embed)
    // H2:  ROWS_*H_                 (ln2 out; RE/SE/AE during embed)
    float* ws = (float*)d_ws;
    float* X  = ws;
    float* RB = X + (size_t)ROWS_ * H_;
    float* H2 = RB + (size_t)ROWS_ * NI_;

    float* HB = RB;
    float* QB = RB + (size_t)ROWS_ * H_;
    float* KB = QB + (size_t)ROWS_ * H_;
    float* VB = KB + (size_t)ROWS_ * H_;
    float* MID = RB;

    float* U_s = RB;
    float* U_a = RB + (size_t)BT_ * KE_;
    float* U_r = RB + (size_t)2 * BT_ * KE_;
    float* RE = H2;
    float* SE = H2 + (size_t)BT_ * H_;
    float* AE = H2 + (size_t)2 * BT_ * H_;

    // ---- embedding ----
    embed_pre_kernel<<<BT_, 256, 0, stream>>>(
        states, actions, rtgs, smean, sstd, W_es, b_es, W_ea, b_ea,
        W_er, b_er, E_t, tsteps, U_s, U_a, U_r);

    dim3 gEmb(H_ / 64, BT_ / 64);
    gemm_kernel<0><<<gEmb, 256, 0, stream>>>(U_s, W_ts, b_ts, SE, BT_, H_, KE_, KE_);
    gemm_kernel<0><<<gEmb, 256, 0, stream>>>(U_a, W_ta, b_ta, AE, BT_, H_, KE_, KE_);
    gemm_kernel<0><<<gEmb, 256, 0, stream>>>(U_r, W_tr, b_tr, RE, BT_, H_, KE_, KE_);

    interleave_eln_kernel<<<ROWS_, 256, 0, stream>>>(RE, SE, AE, eln_g, eln_b, X);

    // ---- transformer layers ----
    dim3 gProj(H_ / 64, ROWS_ / 64);     // 16 x 96
    dim3 gMlp1(NI_ / 64, ROWS_ / 64);    // 64 x 96
    dim3 gAttn(T3_ / 64, NH_, B_);       // 12 x 16 x 8
    for (int l = 0; l < L_; ++l) {
        const size_t wOff = (size_t)l * H_ * H_;
        const size_t bOff = (size_t)l * H_;
        ln_kernel<<<ROWS_, 256, 0, stream>>>(X, ln1_g + bOff, ln1_b + bOff, HB);
        gemm_kernel<0><<<gProj, 256, 0, stream>>>(HB, Wq + wOff, bq + bOff, QB, ROWS_, H_, H_, H_);
        gemm_kernel<0><<<gProj, 256, 0, stream>>>(HB, Wk + wOff, bk + bOff, KB, ROWS_, H_, H_, H_);
        gemm_kernel<0><<<gProj, 256, 0, stream>>>(HB, Wv + wOff, bv + bOff, VB, ROWS_, H_, H_, H_);
        attn_kernel<<<gAttn, 256, 0, stream>>>(QB, KB, VB, amask, HB);   // Y -> HB
        gemm_kernel<1><<<gProj, 256, 0, stream>>>(HB, Wo + wOff, bo + bOff, X, ROWS_, H_, H_, H_);
        ln_kernel<<<ROWS_, 256, 0, stream>>>(X, ln2_g + bOff, ln2_b + bOff, H2);
        gemm_kernel<2><<<gMlp1, 256, 0, stream>>>(H2, W1 + (size_t)l * H_ * NI_, b1 + (size_t)l * NI_,
                                                  MID, ROWS_, NI_, H_, H_);
        gemm_kernel<1><<<gProj, 256, 0, stream>>>(MID, W2 + (size_t)l * NI_ * H_, b2 + bOff,
                                                  X, ROWS_, H_, NI_, NI_);
    }

    head_kernel<<<BT_, 256, 0, stream>>>(X, W_pa, b_pa, out);
}

// Round 2
// 5381.927 us; speedup vs baseline: 3.5380x; 3.5380x over previous
//
#include <hip/hip_runtime.h>
#include <math.h>

// ---- problem dims ----
#define B_    8
#define T_    256
#define S_    16
#define H_    1024
#define NH_   16
#define L_    6
#define NI_   4096
#define TIME_ 8
#define T3_   768           // 3*T
#define DH_   64            // H/NH
#define BT_   2048          // B*T
#define ROWS_ 6144          // B*T3
#define KE_   1032          // H + TIME
#define KEP_  1056          // KE padded to multiple of 32
#define NEGV  (-10000.0f)

typedef unsigned short u16;
typedef short bf16x8 __attribute__((ext_vector_type(8)));   // 8 bf16 in 4 VGPRs
typedef float f32x4 __attribute__((ext_vector_type(4)));

__device__ __forceinline__ float bf2f(u16 u) {
    union { unsigned int i; float f; } x; x.i = ((unsigned int)u) << 16; return x.f;
}
__device__ __forceinline__ u16 f2bf(float f) {
    union { float f; unsigned int i; } x; x.f = f;
    unsigned int r = x.i + 0x7FFFu + ((x.i >> 16) & 1u);   // RNE
    return (u16)(r >> 16);
}
__device__ __forceinline__ float gelu_exact(float x) {
    return x * 0.5f * (1.0f + erff(x * 0.70710678118654752f));
}

// =====================================================================
// bf16 MFMA GEMM: C(M,N) = A(M,K) @ Bt(N,K)^T + bias, 128x128x32 tiles.
// A: bf16 [M][K] row-major.  Bt: bf16 [N][K] row-major (i.e. W^T).
// LDS granule-column-major: granule g = j*128 + row holds elems
// (row, k0 + j*8 .. +7) -> frag ds_read_b128 is <=2-way bank aliased.
// EPI: 0 = bias -> f32, 1 = bias + residual(f32) -> f32,
//      2 = bias -> bf16, 3 = bias + gelu -> bf16
// =====================================================================
template <int EPI>
__global__ __launch_bounds__(256) void mgemm(
    const u16* __restrict__ A, const u16* __restrict__ Bt,
    const float* __restrict__ bias, float* __restrict__ outf,
    u16* __restrict__ outb, const float* __restrict__ res,
    int N, int K)
{
    __shared__ u16 Als[128 * 32];
    __shared__ u16 Bls[128 * 32];
    const int tid = threadIdx.x;
    const int bm = blockIdx.y * 128, bn = blockIdx.x * 128;

    const int lane = tid & 63;
    const int w = tid >> 6;             // wave 0..3
    const int wr = w >> 1, wc = w & 1;  // 2x2 wave grid of 64x64 sub-tiles
    const int lrow = lane & 15;         // m (or n) within 16-tile
    const int lk = lane >> 4;           // k-group 0..3

    f32x4 acc[4][4] = {};

    for (int k0 = 0; k0 < K; k0 += 32) {
        // ---- stage 128x32 A and Bt tiles (granule-column-major) ----
        #pragma unroll
        for (int s = 0; s < 2; ++s) {
            const int g = tid + s * 256;          // granule 0..511
            const int j = g >> 7, m = g & 127;
            ((uint4*)Als)[g] = *(const uint4*)(A + (size_t)(bm + m) * K + k0 + j * 8);
            ((uint4*)Bls)[g] = *(const uint4*)(Bt + (size_t)(bn + m) * K + k0 + j * 8);
        }
        __syncthreads();
        // ---- fragments + MFMA ----
        const bf16x8* Af = (const bf16x8*)Als;
        const bf16x8* Bf = (const bf16x8*)Bls;
        bf16x8 af[4], bfr[4];
        #pragma unroll
        for (int tm = 0; tm < 4; ++tm)
            af[tm] = Af[lk * 128 + wr * 64 + tm * 16 + lrow];
        #pragma unroll
        for (int tn = 0; tn < 4; ++tn)
            bfr[tn] = Bf[lk * 128 + wc * 64 + tn * 16 + lrow];
        #pragma unroll
        for (int tm = 0; tm < 4; ++tm)
            #pragma unroll
            for (int tn = 0; tn < 4; ++tn)
                acc[tm][tn] = __builtin_amdgcn_mfma_f32_16x16x32_bf16(
                    af[tm], bfr[tn], acc[tm][tn], 0, 0, 0);
        __syncthreads();
    }

    // ---- epilogue: D row = quad*4+reg, col = lane&15 (per 16x16 tile) ----
    int cg[4]; float bv[4];
    #pragma unroll
    for (int tn = 0; tn < 4; ++tn) {
        cg[tn] = bn + wc * 64 + tn * 16 + lrow;
        bv[tn] = bias[cg[tn]];
    }
    #pragma unroll
    for (int tm = 0; tm < 4; ++tm) {
        const int rbase = bm + wr * 64 + tm * 16 + lk * 4;
        #pragma unroll
        for (int r = 0; r < 4; ++r) {
            const size_t rowoff = (size_t)(rbase + r) * N;
            #pragma unroll
            for (int tn = 0; tn < 4; ++tn) {
                float v = acc[tm][tn][r] + bv[tn];
                const size_t idx = rowoff + cg[tn];
                if (EPI == 0) outf[idx] = v;
                else if (EPI == 1) outf[idx] = v + res[idx];
                else if (EPI == 2) outb[idx] = f2bf(v);
                else { outb[idx] = f2bf(gelu_exact(v)); }
            }
        }
    }
}

// =====================================================================
// Weight transpose + fp32->bf16: W[K][N] fp32 -> Wt[N][Kpad] bf16
// (zero-filled for k >= K). 32x32 tiles, 256 threads.
// =====================================================================
__global__ __launch_bounds__(256) void convT_kernel(
    const float* __restrict__ W, u16* __restrict__ Wt, int K, int N, int Kpad)
{
    __shared__ float tile[32][33];
    const int k0 = blockIdx.y * 32, n0 = blockIdx.x * 32;
    const int tx = threadIdx.x & 31, ty = threadIdx.x >> 5;   // 32 x 8
    #pragma unroll
    for (int i = 0; i < 32; i += 8) {
        int k = k0 + ty + i;
        tile[ty + i][tx] = (k < K) ? W[(size_t)k * N + n0 + tx] : 0.0f;
    }
    __syncthreads();
    #pragma unroll
    for (int i = 0; i < 32; i += 8) {
        int n = n0 + ty + i;
        Wt[(size_t)n * Kpad + k0 + tx] = f2bf(tile[tx][ty + i]);
    }
}

// pack per-layer q/k/v biases into one fp32[3072]
__global__ __launch_bounds__(256) void pack_bias_kernel(
    const float* __restrict__ bq, const float* __restrict__ bk,
    const float* __restrict__ bv, float* __restrict__ bqkv)
{
    const int i = blockIdx.x * 256 + threadIdx.x;   // 0..3071
    float v;
    if (i < 1024) v = bq[i];
    else if (i < 2048) v = bk[i - 1024];
    else v = bv[i - 2048];
    bqkv[i] = v;
}

// =====================================================================
// embedding pre-stage: writes bf16 U rows [proj(1024), te(8), zeros(24)]
// =====================================================================
__global__ __launch_bounds__(256) void embed_pre_kernel(
    const float* __restrict__ states, const float* __restrict__ actions,
    const float* __restrict__ rtgs, const float* __restrict__ mean,
    const float* __restrict__ stdv, const float* __restrict__ W_es,
    const float* __restrict__ b_es, const float* __restrict__ W_ea,
    const float* __restrict__ b_ea, const float* __restrict__ W_er,
    const float* __restrict__ b_er, const float* __restrict__ E_t,
    const int* __restrict__ timesteps,
    u16* __restrict__ Us, u16* __restrict__ Ua, u16* __restrict__ Ur)
{
    const int bt  = blockIdx.x;
    const int tid = threadIdx.x;
    __shared__ float sn[S_];
    __shared__ float tev[TIME_];
    if (tid < S_) sn[tid] = (states[bt * S_ + tid] - mean[tid]) / (stdv[tid] + 1e-9f);
    if (tid < TIME_) {
        int ts = timesteps[bt];
        tev[tid] = E_t[ts * TIME_ + tid];
    }
    __syncthreads();
    const float av = actions[bt];
    const float rv = rtgs[bt];
    const size_t rowo = (size_t)bt * KEP_;
    #pragma unroll
    for (int u = 0; u < 4; ++u) {
        int n = tid + u * 256;
        float accs = b_es[n];
        #pragma unroll
        for (int i = 0; i < S_; ++i) accs += sn[i] * W_es[i * H_ + n];
        Us[rowo + n] = f2bf(accs);
        Ua[rowo + n] = f2bf(av * W_ea[n] + b_ea[n]);
        Ur[rowo + n] = f2bf(rv * W_er[n] + b_er[n]);
    }
    if (tid < TIME_) {
        u16 tv = f2bf(tev[tid]);
        Us[rowo + H_ + tid] = tv;
        Ua[rowo + H_ + tid] = tv;
        Ur[rowo + H_ + tid] = tv;
    }
    if (tid < KEP_ - KE_) {   // zero pad cols 1032..1055
        Us[rowo + KE_ + tid] = 0;
        Ua[rowo + KE_ + tid] = 0;
        Ur[rowo + KE_ + tid] = 0;
    }
}

// =====================================================================
// LayerNorm over rows of 1024; templated output dtype
// =====================================================================
template <bool BF16OUT>
__device__ __forceinline__ void ln_body(const float* __restrict__ src,
                                        const float* __restrict__ g,
                                        const float* __restrict__ b,
                                        void* __restrict__ dst,
                                        float* red, int tid)
{
    float v[4];
    #pragma unroll
    for (int u = 0; u < 4; ++u) v[u] = src[tid + u * 256];
    float s = v[0] + v[1] + v[2] + v[3];
    red[tid] = s; __syncthreads();
    for (int off = 128; off > 0; off >>= 1) {
        if (tid < off) red[tid] += red[tid + off];
        __syncthreads();
    }
    const float mean = red[0] * (1.0f / H_);
    __syncthreads();
    float ss = 0.0f;
    #pragma unroll
    for (int u = 0; u < 4; ++u) { float d = v[u] - mean; ss += d * d; }
    red[tid] = ss; __syncthreads();
    for (int off = 128; off > 0; off >>= 1) {
        if (tid < off) red[tid] += red[tid + off];
        __syncthreads();
    }
    const float var = red[0] * (1.0f / H_);
    const float rs = rsqrtf(var + 1e-5f);
    #pragma unroll
    for (int u = 0; u < 4; ++u) {
        int col = tid + u * 256;
        float y = (v[u] - mean) * rs * g[col] + b[col];
        if (BF16OUT) ((u16*)dst)[col] = f2bf(y);
        else ((float*)dst)[col] = y;
    }
}

__global__ __launch_bounds__(256) void ln_bf16_kernel(
    const float* __restrict__ X, const float* __restrict__ g,
    const float* __restrict__ b, u16* __restrict__ Y)
{
    __shared__ float red[256];
    const size_t row = blockIdx.x;
    ln_body<true>(X + row * H_, g, b, Y + row * H_, red, threadIdx.x);
}

// gather re/se/ae interleaved + embedding LN -> fp32 X
__global__ __launch_bounds__(256) void interleave_eln_kernel(
    const float* __restrict__ RE, const float* __restrict__ SE,
    const float* __restrict__ AE, const float* __restrict__ g,
    const float* __restrict__ b, float* __restrict__ X)
{
    __shared__ float red[256];
    const int row = blockIdx.x;
    const int bi = row / T3_;
    const int rem = row % T3_;
    const int t = rem / 3, slot = rem % 3;
    const float* src = (slot == 0 ? RE : (slot == 1 ? SE : AE)) + (size_t)(bi * T_ + t) * H_;
    ln_body<false>(src, g, b, X + (size_t)row * H_, red, threadIdx.x);
}

// =====================================================================
// flash-style causal attention, fp32 math, bf16 QKV in / bf16 Y out.
// QKV layout: [row = b*768+t][3072] with Q at col h*64, K +1024, V +2048.
// =====================================================================
__global__ __launch_bounds__(256) void attn_kernel(
    const u16* __restrict__ QKV, const float* __restrict__ amask,
    u16* __restrict__ Y)
{
    const int qt = blockIdx.x;   // 0..11
    const int h  = blockIdx.y;   // 0..15
    const int b  = blockIdx.z;   // 0..7
    const int tid = threadIdx.x;
    const int tx = tid & 15, ty = tid >> 4;
    const int r0 = ty * 4, c0 = tx * 4;

    __shared__ float qs[64][65];
    __shared__ float kps[64][65];
    __shared__ float vs[64][65];
    __shared__ float red[64][17];
    __shared__ float padv[64];

    const u16* Qp = QKV + (size_t)b * T3_ * 3072 + h * 64;
    const u16* Kp = Qp + 1024;
    const u16* Vp = Qp + 2048;

    #pragma unroll
    for (int c = 0; c < 16; ++c) {
        int idx = c * 256 + tid;
        int rr = idx >> 6, cc = idx & 63;
        qs[rr][cc] = bf2f(Qp[(size_t)(qt * 64 + rr) * 3072 + cc]);
    }

    float m_i[4], l_i[4], o[4][4];
    #pragma unroll
    for (int j = 0; j < 4; ++j) {
        m_i[j] = -3.0e30f; l_i[j] = 0.0f;
        #pragma unroll
        for (int k = 0; k < 4; ++k) o[j][k] = 0.0f;
    }

    for (int kt = 0; kt <= qt; ++kt) {
        #pragma unroll
        for (int c = 0; c < 16; ++c) {
            int idx = c * 256 + tid;
            int rr = idx >> 6, cc = idx & 63;
            kps[rr][cc] = bf2f(Kp[(size_t)(kt * 64 + rr) * 3072 + cc]);
            vs[rr][cc]  = bf2f(Vp[(size_t)(kt * 64 + rr) * 3072 + cc]);
        }
        if (tid < 64) {
            int j = kt * 64 + tid;
            padv[tid] = (1.0f - amask[b * T_ + j / 3]) * NEGV;
        }
        __syncthreads();

        float s[4][4];
        #pragma unroll
        for (int jj = 0; jj < 4; ++jj)
            #pragma unroll
            for (int kk = 0; kk < 4; ++kk) s[jj][kk] = 0.0f;
        for (int i = 0; i < 64; ++i) {
            float a[4], wv[4];
            #pragma unroll
            for (int j = 0; j < 4; ++j) a[j] = qs[r0 + j][i];
            #pragma unroll
            for (int j = 0; j < 4; ++j) wv[j] = kps[c0 + j][i];
            #pragma unroll
            for (int jj = 0; jj < 4; ++jj)
                #pragma unroll
                for (int kk = 0; kk < 4; ++kk)
                    s[jj][kk] += a[jj] * wv[kk];
        }
        float tmax[4];
        #pragma unroll
        for (int jj = 0; jj < 4; ++jj) {
            const int qr = qt * 64 + r0 + jj;
            tmax[jj] = -3.0e30f;
            #pragma unroll
            for (int kk = 0; kk < 4; ++kk) {
                const int jc = kt * 64 + c0 + kk;
                float val = (jc <= qr) ? s[jj][kk] * 0.125f : NEGV;
                val += padv[c0 + kk];
                s[jj][kk] = val;
                tmax[jj] = fmaxf(tmax[jj], val);
            }
        }
        #pragma unroll
        for (int jj = 0; jj < 4; ++jj) red[r0 + jj][tx] = tmax[jj];
        __syncthreads();
        float mnew[4], alpha[4];
        #pragma unroll
        for (int jj = 0; jj < 4; ++jj) {
            float rm = -3.0e30f;
            #pragma unroll
            for (int x = 0; x < 16; ++x) rm = fmaxf(rm, red[r0 + jj][x]);
            mnew[jj] = fmaxf(m_i[jj], rm);
            alpha[jj] = expf(m_i[jj] - mnew[jj]);
        }
        __syncthreads();
        float rsum[4];
        #pragma unroll
        for (int jj = 0; jj < 4; ++jj) {
            float sm = 0.0f;
            #pragma unroll
            for (int kk = 0; kk < 4; ++kk) {
                float p = expf(s[jj][kk] - mnew[jj]);
                s[jj][kk] = p; sm += p;
            }
            rsum[jj] = sm;
        }
        #pragma unroll
        for (int jj = 0; jj < 4; ++jj) red[r0 + jj][tx] = rsum[jj];
        #pragma unroll
        for (int jj = 0; jj < 4; ++jj)
            #pragma unroll
            for (int kk = 0; kk < 4; ++kk)
                kps[r0 + jj][c0 + kk] = s[jj][kk];
        __syncthreads();
        #pragma unroll
        for (int jj = 0; jj < 4; ++jj) {
            float tot = 0.0f;
            #pragma unroll
            for (int x = 0; x < 16; ++x) tot += red[r0 + jj][x];
            l_i[jj] = l_i[jj] * alpha[jj] + tot;
            m_i[jj] = mnew[jj];
        }
        #pragma unroll
        for (int jj = 0; jj < 4; ++jj)
            #pragma unroll
            for (int kk = 0; kk < 4; ++kk) o[jj][kk] *= alpha[jj];
        for (int c = 0; c < 64; ++c) {
            float pv[4], vv[4];
            #pragma unroll
            for (int jj = 0; jj < 4; ++jj) pv[jj] = kps[r0 + jj][c];
            #pragma unroll
            for (int kk = 0; kk < 4; ++kk) vv[kk] = vs[c][c0 + kk];
            #pragma unroll
            for (int jj = 0; jj < 4; ++jj)
                #pragma unroll
                for (int kk = 0; kk < 4; ++kk)
                    o[jj][kk] += pv[jj] * vv[kk];
        }
        __syncthreads();
    }
    #pragma unroll
    for (int jj = 0; jj < 4; ++jj) {
        const int qr = qt * 64 + r0 + jj;
        const float inv = 1.0f / l_i[jj];
        #pragma unroll
        for (int kk = 0; kk < 4; ++kk)
            Y[((size_t)b * T3_ + qr) * H_ + h * 64 + c0 + kk] = f2bf(o[jj][kk] * inv);
    }
}

// =====================================================================
// action head
// =====================================================================
__global__ __launch_bounds__(256) void head_kernel(
    const float* __restrict__ X, const float* __restrict__ W_pa,
    const float* __restrict__ b_pa, float* __restrict__ out)
{
    __shared__ float red[256];
    const int row = blockIdx.x;
    const int b = row / T_, t = row % T_;
    const float* x = X + ((size_t)b * T3_ + 3 * t + 1) * H_;
    const int tid = threadIdx.x;
    float s = 0.0f;
    #pragma unroll
    for (int u = 0; u < 4; ++u) {
        int col = tid + u * 256;
        s += x[col] * W_pa[col];
    }
    red[tid] = s; __syncthreads();
    for (int off = 128; off > 0; off >>= 1) {
        if (tid < off) red[tid] += red[tid + off];
        __syncthreads();
    }
    if (tid == 0) out[row] = red[0] + b_pa[0];
}

// =====================================================================
extern "C" void kernel_launch(void* const* d_in, const int* in_sizes, int n_in,
                              void* d_out, int out_size, void* d_ws, size_t ws_size,
                              hipStream_t stream)
{
    const float* states  = (const float*)d_in[0];
    const float* actions = (const float*)d_in[1];
    const float* rtgs    = (const float*)d_in[2];
    const float* amask   = (const float*)d_in[3];
    const float* smean   = (const float*)d_in[4];
    const float* sstd    = (const float*)d_in[5];
    const float* W_es    = (const float*)d_in[6];
    const float* b_es    = (const float*)d_in[7];
    const float* W_ea    = (const float*)d_in[8];
    const float* b_ea    = (const float*)d_in[9];
    const float* W_er    = (const float*)d_in[10];
    const float* b_er    = (const float*)d_in[11];
    const float* E_t     = (const float*)d_in[12];
    const float* W_ts    = (const float*)d_in[13];
    const float* b_ts    = (const float*)d_in[14];
    const float* W_ta    = (const float*)d_in[15];
    const float* b_ta    = (const float*)d_in[16];
    const float* W_tr    = (const float*)d_in[17];
    const float* b_tr    = (const float*)d_in[18];
    const float* eln_g   = (const float*)d_in[19];
    const float* eln_b   = (const float*)d_in[20];
    const float* ln1_g   = (const float*)d_in[21];
    const float* ln1_b   = (const float*)d_in[22];
    const float* ln2_g   = (const float*)d_in[23];
    const float* ln2_b   = (const float*)d_in[24];
    const float* Wq      = (const float*)d_in[25];
    const float* bq      = (const float*)d_in[26];
    const float* Wk      = (const float*)d_in[27];
    const float* bk      = (const float*)d_in[28];
    const float* Wv      = (const float*)d_in[29];
    const float* bv      = (const float*)d_in[30];
    const float* Wo      = (const float*)d_in[31];
    const float* bo      = (const float*)d_in[32];
    const float* W1      = (const float*)d_in[33];
    const float* b1      = (const float*)d_in[34];
    const float* W2      = (const float*)d_in[35];
    const float* b2      = (const float*)d_in[36];
    const float* W_pa    = (const float*)d_in[37];
    const float* b_pa    = (const float*)d_in[38];
    const int*   tsteps  = (const int*)d_in[39];
    float* out = (float*)d_out;

    // ---- workspace layout (bytes) ----
    char* base = (char*)d_ws;
    float* X    = (float*)base;                        // 25,165,824
    u16*   Hb   = (u16*)(base + 25165824);             // 12,582,912
    u16*   QKVb = (u16*)(base + 37748736);             // 37,748,736
    u16*   MIDb = (u16*)(base + 75497472);             // 50,331,648
    u16*   Wbuf = (u16*)(base + 125829120);            // 25,165,824 (end 150,994,944)

    // aliases (sequentially disjoint lifetimes)
    float* bqkv = (float*)MIDb;                        // 12 KB, used during QKV gemm
    u16* U_s = MIDb;                                   // embed phase
    u16* U_a = MIDb + (size_t)BT_ * KEP_;
    u16* U_r = MIDb + (size_t)2 * BT_ * KEP_;
    float* SE = (float*)QKVb;                          // embed phase
    float* AE = SE + (size_t)BT_ * H_;
    float* RE = AE + (size_t)BT_ * H_;
    u16* Wtst = Wbuf;                                  // embed weights
    u16* Wtat = Wbuf + (size_t)H_ * KEP_;
    u16* Wtrt = Wbuf + (size_t)2 * H_ * KEP_;

    // layer weight slots in Wbuf (elements)
    u16* WQKVt = Wbuf;                                 // [3072][1024]
    u16* Wot   = Wbuf + (size_t)3072 * 1024;           // [1024][1024]
    u16* W1t   = Wbuf + (size_t)4096 * 1024;           // [4096][1024]
    u16* W2t   = Wbuf + (size_t)8192 * 1024;           // [1024][4096]

    // ---- embedding ----
    embed_pre_kernel<<<BT_, 256, 0, stream>>>(
        states, actions, rtgs, smean, sstd, W_es, b_es, W_ea, b_ea,
        W_er, b_er, E_t, tsteps, U_s, U_a, U_r);

    dim3 gCvE(H_ / 32, KEP_ / 32);                     // 32 x 33
    convT_kernel<<<gCvE, 256, 0, stream>>>(W_ts, Wtst, KE_, H_, KEP_);
    convT_kernel<<<gCvE, 256, 0, stream>>>(W_ta, Wtat, KE_, H_, KEP_);
    convT_kernel<<<gCvE, 256, 0, stream>>>(W_tr, Wtrt, KE_, H_, KEP_);

    dim3 gEmb(H_ / 128, BT_ / 128);                    // 8 x 16
    mgemm<0><<<gEmb, 256, 0, stream>>>(U_s, Wtst, b_ts, SE, nullptr, nullptr, H_, KEP_);
    mgemm<0><<<gEmb, 256, 0, stream>>>(U_a, Wtat, b_ta, AE, nullptr, nullptr, H_, KEP_);
    mgemm<0><<<gEmb, 256, 0, stream>>>(U_r, Wtrt, b_tr, RE, nullptr, nullptr, H_, KEP_);

    interleave_eln_kernel<<<ROWS_, 256, 0, stream>>>(RE, SE, AE, eln_g, eln_b, X);

    // ---- transformer layers ----
    dim3 gCv1(H_ / 32, H_ / 32);                       // 1024x1024 transpose
    dim3 gCvM1(NI_ / 32, H_ / 32);                     // W1: K=1024,N=4096
    dim3 gCvM2(H_ / 32, NI_ / 32);                     // W2: K=4096,N=1024
    dim3 gQKV(3072 / 128, ROWS_ / 128);                // 24 x 48
    dim3 gO(H_ / 128, ROWS_ / 128);                    // 8 x 48
    dim3 gM1(NI_ / 128, ROWS_ / 128);                  // 32 x 48
    dim3 gAttn(T3_ / 64, NH_, B_);                     // 12 x 16 x 8

    for (int l = 0; l < L_; ++l) {
        const size_t wOff = (size_t)l * H_ * H_;
        const size_t bOff = (size_t)l * H_;
        const size_t w1Off = (size_t)l * H_ * NI_;
        const size_t b1Off = (size_t)l * NI_;

        // per-layer weight conversion into rotating Wbuf
        convT_kernel<<<gCv1, 256, 0, stream>>>(Wq + wOff, WQKVt, H_, H_, H_);
        convT_kernel<<<gCv1, 256, 0, stream>>>(Wk + wOff, WQKVt + (size_t)1024 * 1024, H_, H_, H_);
        convT_kernel<<<gCv1, 256, 0, stream>>>(Wv + wOff, WQKVt + (size_t)2048 * 1024, H_, H_, H_);
        convT_kernel<<<gCv1, 256, 0, stream>>>(Wo + wOff, Wot, H_, H_, H_);
        convT_kernel<<<gCvM1, 256, 0, stream>>>(W1 + w1Off, W1t, H_, NI_, H_);
        convT_kernel<<<gCvM2, 256, 0, stream>>>(W2 + w1Off, W2t, NI_, H_, NI_);
        pack_bias_kernel<<<12, 256, 0, stream>>>(bq + bOff, bk + bOff, bv + bOff, bqkv);

        ln_bf16_kernel<<<ROWS_, 256, 0, stream>>>(X, ln1_g + bOff, ln1_b + bOff, Hb);
        mgemm<2><<<gQKV, 256, 0, stream>>>(Hb, WQKVt, bqkv, nullptr, QKVb, nullptr, 3072, H_);
        attn_kernel<<<gAttn, 256, 0, stream>>>(QKVb, amask, Hb);
        mgemm<1><<<gO, 256, 0, stream>>>(Hb, Wot, bo + bOff, X, nullptr, X, H_, H_);
        ln_bf16_kernel<<<ROWS_, 256, 0, stream>>>(X, ln2_g + bOff, ln2_b + bOff, Hb);
        mgemm<3><<<gM1, 256, 0, stream>>>(Hb, W1t, b1 + b1Off, nullptr, MIDb, nullptr, NI_, H_);
        mgemm<1><<<gO, 256, 0, stream>>>(MIDb, W2t, b2 + bOff, X, nullptr, X, H_, NI_);
    }

    head_kernel<<<BT_, 256, 0, stream>>>(X, W_pa, b_pa, out);
}

// Round 3
// 3532.671 us; speedup vs baseline: 5.3900x; 1.5235x over previous
//
#include <hip/hip_runtime.h>
#include <math.h>

// ---- problem dims ----
#define B_    8
#define T_    256
#define S_    16
#define H_    1024
#define NH_   16
#define L_    6
#define NI_   4096
#define TIME_ 8
#define T3_   768           // 3*T
#define DH_   64            // H/NH
#define BT_   2048          // B*T
#define ROWS_ 6144          // B*T3
#define KE_   1032          // H + TIME
#define KEP_  1056          // KE padded to multiple of 32
#define NEGV  (-10000.0f)

typedef unsigned short u16;
typedef short bf16x8 __attribute__((ext_vector_type(8)));   // 8 bf16 in 4 VGPRs
typedef float f32x4 __attribute__((ext_vector_type(4)));

__device__ __forceinline__ float bf2f(u16 u) {
    union { unsigned int i; float f; } x; x.i = ((unsigned int)u) << 16; return x.f;
}
__device__ __forceinline__ u16 f2bf(float f) {
    union { float f; unsigned int i; } x; x.f = f;
    unsigned int r = x.i + 0x7FFFu + ((x.i >> 16) & 1u);   // RNE
    return (u16)(r >> 16);
}
__device__ __forceinline__ float gelu_exact(float x) {
    return x * 0.5f * (1.0f + erff(x * 0.70710678118654752f));
}

// async global->LDS 16B: lds_base must be wave-uniform; data lands at
// base + lane*16 (m97 pattern, cdna_hip_programming.md §5).
__device__ __forceinline__ void gll16(const u16* g, u16* l) {
    __builtin_amdgcn_global_load_lds(
        (const __attribute__((address_space(1))) unsigned int*)g,
        (__attribute__((address_space(3))) unsigned int*)l,
        16, 0, 0);
}

// =====================================================================
// bf16 MFMA GEMM: C(M,N) = A(M,K) @ Bt(N,K)^T + bias, BMx128x32 tiles.
// LDS granule layout: granule g = j*BM + row holds (row, k0+j*8 .. +7);
// staged via global_load_lds (wave-uniform base + lane*16).
// EPI: 0 = bias -> f32, 1 = bias + residual(f32) -> f32,
//      2 = bias -> bf16, 3 = bias + gelu -> bf16
// =====================================================================
template <int EPI, int BM>
__global__ __launch_bounds__(256) void mgemm(
    const u16* __restrict__ A, const u16* __restrict__ Bt,
    const float* __restrict__ bias, float* __restrict__ outf,
    u16* __restrict__ outb, const float* __restrict__ res,
    int N, int K)
{
    constexpr int MT = (BM == 128) ? 4 : 2;     // 16-row m-tiles per wave
    __shared__ u16 Als[BM * 32];
    __shared__ u16 Bls[128 * 32];
    const int tid = threadIdx.x;
    const int bm = blockIdx.y * BM, bn = blockIdx.x * 128;

    const int lane = tid & 63;
    const int w = tid >> 6;                      // wave 0..3
    const int wr = (BM == 128) ? (w >> 1) : (w & 1);
    const int wc = (BM == 128) ? (w & 1) : (w >> 1);
    const int lrow = lane & 15;
    const int lk = lane >> 4;

    f32x4 acc[MT][4] = {};

    for (int k0 = 0; k0 < K; k0 += 32) {
        // ---- async stage A tile (BM x 32) ----
        if (BM == 128) {
            #pragma unroll
            for (int s = 0; s < 2; ++s) {
                const int gb = w * 64 + s * 256;          // wave-uniform granule base
                const int j = gb >> 7, m0 = gb & 127;
                gll16(A + (size_t)(bm + m0 + lane) * K + k0 + j * 8, Als + gb * 8);
            }
        } else {
            const int gb = w * 64;
            gll16(A + (size_t)(bm + lane) * K + k0 + w * 8, Als + gb * 8);
        }
        // ---- async stage Bt tile (128 x 32) ----
        #pragma unroll
        for (int s = 0; s < 2; ++s) {
            const int gb = w * 64 + s * 256;
            const int j = gb >> 7, m0 = gb & 127;
            gll16(Bt + (size_t)(bn + m0 + lane) * K + k0 + j * 8, Bls + gb * 8);
        }
        __syncthreads();
        // ---- fragments + MFMA ----
        const bf16x8* Af = (const bf16x8*)Als;
        const bf16x8* Bf = (const bf16x8*)Bls;
        bf16x8 af[MT], bfr[4];
        #pragma unroll
        for (int tm = 0; tm < MT; ++tm)
            af[tm] = Af[lk * BM + wr * (MT * 16) + tm * 16 + lrow];
        #pragma unroll
        for (int tn = 0; tn < 4; ++tn)
            bfr[tn] = Bf[lk * 128 + wc * 64 + tn * 16 + lrow];
        #pragma unroll
        for (int tm = 0; tm < MT; ++tm)
            #pragma unroll
            for (int tn = 0; tn < 4; ++tn)
                acc[tm][tn] = __builtin_amdgcn_mfma_f32_16x16x32_bf16(
                    af[tm], bfr[tn], acc[tm][tn], 0, 0, 0);
        __syncthreads();
    }

    // ---- epilogue: D row = quad*4+reg, col = lane&15 (per 16x16 tile) ----
    int cg[4]; float bv[4];
    #pragma unroll
    for (int tn = 0; tn < 4; ++tn) {
        cg[tn] = bn + wc * 64 + tn * 16 + lrow;
        bv[tn] = bias[cg[tn]];
    }
    #pragma unroll
    for (int tm = 0; tm < MT; ++tm) {
        const int rbase = bm + wr * (MT * 16) + tm * 16 + lk * 4;
        #pragma unroll
        for (int r = 0; r < 4; ++r) {
            const size_t rowoff = (size_t)(rbase + r) * N;
            #pragma unroll
            for (int tn = 0; tn < 4; ++tn) {
                float v = acc[tm][tn][r] + bv[tn];
                const size_t idx = rowoff + cg[tn];
                if (EPI == 0) outf[idx] = v;
                else if (EPI == 1) outf[idx] = v + res[idx];
                else if (EPI == 2) outb[idx] = f2bf(v);
                else { outb[idx] = f2bf(gelu_exact(v)); }
            }
        }
    }
}

// =====================================================================
// Weight transpose + fp32->bf16: W[K][N] fp32 -> Wt[N][Kpad] bf16
// =====================================================================
__global__ __launch_bounds__(256) void convT_kernel(
    const float* __restrict__ W, u16* __restrict__ Wt, int K, int N, int Kpad)
{
    __shared__ float tile[32][33];
    const int k0 = blockIdx.y * 32, n0 = blockIdx.x * 32;
    const int tx = threadIdx.x & 31, ty = threadIdx.x >> 5;   // 32 x 8
    #pragma unroll
    for (int i = 0; i < 32; i += 8) {
        int k = k0 + ty + i;
        tile[ty + i][tx] = (k < K) ? W[(size_t)k * N + n0 + tx] : 0.0f;
    }
    __syncthreads();
    #pragma unroll
    for (int i = 0; i < 32; i += 8) {
        int n = n0 + ty + i;
        Wt[(size_t)n * Kpad + k0 + tx] = f2bf(tile[tx][ty + i]);
    }
}

// pack per-layer q/k/v biases into one fp32[3072]
__global__ __launch_bounds__(256) void pack_bias_kernel(
    const float* __restrict__ bq, const float* __restrict__ bk,
    const float* __restrict__ bv, float* __restrict__ bqkv)
{
    const int i = blockIdx.x * 256 + threadIdx.x;
    float v;
    if (i < 1024) v = bq[i];
    else if (i < 2048) v = bk[i - 1024];
    else v = bv[i - 2048];
    bqkv[i] = v;
}

// =====================================================================
// embedding pre-stage
// =====================================================================
__global__ __launch_bounds__(256) void embed_pre_kernel(
    const float* __restrict__ states, const float* __restrict__ actions,
    const float* __restrict__ rtgs, const float* __restrict__ mean,
    const float* __restrict__ stdv, const float* __restrict__ W_es,
    const float* __restrict__ b_es, const float* __restrict__ W_ea,
    const float* __restrict__ b_ea, const float* __restrict__ W_er,
    const float* __restrict__ b_er, const float* __restrict__ E_t,
    const int* __restrict__ timesteps,
    u16* __restrict__ Us, u16* __restrict__ Ua, u16* __restrict__ Ur)
{
    const int bt  = blockIdx.x;
    const int tid = threadIdx.x;
    __shared__ float sn[S_];
    __shared__ float tev[TIME_];
    if (tid < S_) sn[tid] = (states[bt * S_ + tid] - mean[tid]) / (stdv[tid] + 1e-9f);
    if (tid < TIME_) {
        int ts = timesteps[bt];
        tev[tid] = E_t[ts * TIME_ + tid];
    }
    __syncthreads();
    const float av = actions[bt];
    const float rv = rtgs[bt];
    const size_t rowo = (size_t)bt * KEP_;
    #pragma unroll
    for (int u = 0; u < 4; ++u) {
        int n = tid + u * 256;
        float accs = b_es[n];
        #pragma unroll
        for (int i = 0; i < S_; ++i) accs += sn[i] * W_es[i * H_ + n];
        Us[rowo + n] = f2bf(accs);
        Ua[rowo + n] = f2bf(av * W_ea[n] + b_ea[n]);
        Ur[rowo + n] = f2bf(rv * W_er[n] + b_er[n]);
    }
    if (tid < TIME_) {
        u16 tv = f2bf(tev[tid]);
        Us[rowo + H_ + tid] = tv;
        Ua[rowo + H_ + tid] = tv;
        Ur[rowo + H_ + tid] = tv;
    }
    if (tid < KEP_ - KE_) {
        Us[rowo + KE_ + tid] = 0;
        Ua[rowo + KE_ + tid] = 0;
        Ur[rowo + KE_ + tid] = 0;
    }
}

// =====================================================================
// LayerNorm over rows of 1024
// =====================================================================
template <bool BF16OUT>
__device__ __forceinline__ void ln_body(const float* __restrict__ src,
                                        const float* __restrict__ g,
                                        const float* __restrict__ b,
                                        void* __restrict__ dst,
                                        float* red, int tid)
{
    float v[4];
    #pragma unroll
    for (int u = 0; u < 4; ++u) v[u] = src[tid + u * 256];
    float s = v[0] + v[1] + v[2] + v[3];
    red[tid] = s; __syncthreads();
    for (int off = 128; off > 0; off >>= 1) {
        if (tid < off) red[tid] += red[tid + off];
        __syncthreads();
    }
    const float mean = red[0] * (1.0f / H_);
    __syncthreads();
    float ss = 0.0f;
    #pragma unroll
    for (int u = 0; u < 4; ++u) { float d = v[u] - mean; ss += d * d; }
    red[tid] = ss; __syncthreads();
    for (int off = 128; off > 0; off >>= 1) {
        if (tid < off) red[tid] += red[tid + off];
        __syncthreads();
    }
    const float var = red[0] * (1.0f / H_);
    const float rs = rsqrtf(var + 1e-5f);
    #pragma unroll
    for (int u = 0; u < 4; ++u) {
        int col = tid + u * 256;
        float y = (v[u] - mean) * rs * g[col] + b[col];
        if (BF16OUT) ((u16*)dst)[col] = f2bf(y);
        else ((float*)dst)[col] = y;
    }
}

__global__ __launch_bounds__(256) void ln_bf16_kernel(
    const float* __restrict__ X, const float* __restrict__ g,
    const float* __restrict__ b, u16* __restrict__ Y)
{
    __shared__ float red[256];
    const size_t row = blockIdx.x;
    ln_body<true>(X + row * H_, g, b, Y + row * H_, red, threadIdx.x);
}

__global__ __launch_bounds__(256) void interleave_eln_kernel(
    const float* __restrict__ RE, const float* __restrict__ SE,
    const float* __restrict__ AE, const float* __restrict__ g,
    const float* __restrict__ b, float* __restrict__ X)
{
    __shared__ float red[256];
    const int row = blockIdx.x;
    const int bi = row / T3_;
    const int rem = row % T3_;
    const int t = rem / 3, slot = rem % 3;
    const float* src = (slot == 0 ? RE : (slot == 1 ? SE : AE)) + (size_t)(bi * T_ + t) * H_;
    ln_body<false>(src, g, b, X + (size_t)row * H_, red, threadIdx.x);
}

// =====================================================================
// MFMA flash attention. Block = 64 Q-rows x (head, batch); wave = 16 rows.
// QK^T: A=Q frag (regs), B=K^T straight from row-major K tile in LDS.
// PV:   A=P (LDS round-trip, C-layout -> A-layout), B=V^T from transposed
//       V tile in LDS. Online softmax stats in registers (shfl over 16 lanes).
// =====================================================================
__global__ __launch_bounds__(256) void attn_kernel(
    const u16* __restrict__ QKV, const float* __restrict__ amask,
    u16* __restrict__ Y)
{
    const int qt = blockIdx.x;   // 0..11
    const int h  = blockIdx.y;   // 0..15
    const int b  = blockIdx.z;   // 0..7
    const int tid = threadIdx.x;
    const int lane = tid & 63, w = tid >> 6;
    const int l15 = lane & 15, quad = lane >> 4;

    __shared__ u16 Kls[64][72];      // row-major K tile (+8 pad)
    __shared__ u16 Vt[64][72];       // transposed V tile: Vt[dh][token]
    __shared__ u16 Pls[4][16][72];   // per-wave P tile
    __shared__ float padv[64];

    const u16* Qbase = QKV + (size_t)b * T3_ * 3072 + h * 64;
    const u16* Kbase = Qbase + 1024;
    const u16* Vbase = Qbase + 2048;

    // Q fragments for this wave's 16 rows (held in regs for all K-tiles)
    bf16x8 qf[2];
    {
        const u16* qp = Qbase + (size_t)(qt * 64 + w * 16 + l15) * 3072 + quad * 8;
        qf[0] = *(const bf16x8*)qp;
        qf[1] = *(const bf16x8*)(qp + 32);
    }

    float m_i[4], l_i[4];
    f32x4 o[4] = {};
    #pragma unroll
    for (int r = 0; r < 4; ++r) { m_i[r] = -3.0e30f; l_i[r] = 0.0f; }

    const int qr0 = qt * 64 + w * 16 + quad * 4;   // + r = global q row in seq

    for (int kt = 0; kt <= qt; ++kt) {
        // ---- stage K row-major, V transposed ----
        #pragma unroll
        for (int s = 0; s < 2; ++s) {
            const int c = tid + s * 256;             // chunk 0..511
            const int tok = c >> 3, cb = c & 7;
            const size_t go = (size_t)(kt * 64 + tok) * 3072 + cb * 8;
            *(uint4*)&Kls[tok][cb * 8] = *(const uint4*)(Kbase + go);
            uint4 vv = *(const uint4*)(Vbase + go);
            const u16* vs = (const u16*)&vv;
            #pragma unroll
            for (int j = 0; j < 8; ++j) Vt[cb * 8 + j][tok] = vs[j];
        }
        if (tid < 64)
            padv[tid] = (1.0f - amask[b * T_ + (kt * 64 + tid) / 3]) * NEGV;
        __syncthreads();

        // ---- S = Q K^T (16 x 64 per wave) ----
        f32x4 sacc[4];
        #pragma unroll
        for (int nt = 0; nt < 4; ++nt) {
            bf16x8 kf0 = *(const bf16x8*)&Kls[nt * 16 + l15][quad * 8];
            bf16x8 kf1 = *(const bf16x8*)&Kls[nt * 16 + l15][32 + quad * 8];
            f32x4 z = {};
            z = __builtin_amdgcn_mfma_f32_16x16x32_bf16(qf[0], kf0, z, 0, 0, 0);
            sacc[nt] = __builtin_amdgcn_mfma_f32_16x16x32_bf16(qf[1], kf1, z, 0, 0, 0);
        }

        // ---- mask + online softmax (rows = quad*4+r, col = nt*16+l15) ----
        float sv[4][4];                    // [nt][r]
        float rmax[4] = {-3.0e30f, -3.0e30f, -3.0e30f, -3.0e30f};
        #pragma unroll
        for (int nt = 0; nt < 4; ++nt) {
            const int jc = kt * 64 + nt * 16 + l15;
            const float pv = padv[nt * 16 + l15];
            #pragma unroll
            for (int r = 0; r < 4; ++r) {
                float v = (jc <= qr0 + r) ? sacc[nt][r] * 0.125f : NEGV;
                v += pv;
                sv[nt][r] = v;
                rmax[r] = fmaxf(rmax[r], v);
            }
        }
        #pragma unroll
        for (int m = 1; m < 16; m <<= 1)
            #pragma unroll
            for (int r = 0; r < 4; ++r)
                rmax[r] = fmaxf(rmax[r], __shfl_xor(rmax[r], m, 64));
        float al[4], rsum[4];
        #pragma unroll
        for (int r = 0; r < 4; ++r) {
            const float mn = fmaxf(m_i[r], rmax[r]);
            al[r] = __expf(m_i[r] - mn);
            m_i[r] = mn;
            float sum = 0.0f;
            #pragma unroll
            for (int nt = 0; nt < 4; ++nt) {
                float p = __expf(sv[nt][r] - mn);
                sv[nt][r] = p; sum += p;
            }
            rsum[r] = sum;
        }
        #pragma unroll
        for (int m = 1; m < 16; m <<= 1)
            #pragma unroll
            for (int r = 0; r < 4; ++r)
                rsum[r] += __shfl_xor(rsum[r], m, 64);
        #pragma unroll
        for (int r = 0; r < 4; ++r)
            l_i[r] = l_i[r] * al[r] + rsum[r];

        // ---- P -> LDS (C-layout write), O *= alpha ----
        #pragma unroll
        for (int nt = 0; nt < 4; ++nt)
            #pragma unroll
            for (int r = 0; r < 4; ++r)
                Pls[w][quad * 4 + r][nt * 16 + l15] = f2bf(sv[nt][r]);
        #pragma unroll
        for (int dt = 0; dt < 4; ++dt)
            #pragma unroll
            for (int r = 0; r < 4; ++r)
                o[dt][r] *= al[r];

        // ---- O += P V  (A-frag from Pls, B-frag from Vt) ----
        bf16x8 pf0 = *(const bf16x8*)&Pls[w][l15][quad * 8];
        bf16x8 pf1 = *(const bf16x8*)&Pls[w][l15][32 + quad * 8];
        #pragma unroll
        for (int dt = 0; dt < 4; ++dt) {
            bf16x8 vf0 = *(const bf16x8*)&Vt[dt * 16 + l15][quad * 8];
            bf16x8 vf1 = *(const bf16x8*)&Vt[dt * 16 + l15][32 + quad * 8];
            o[dt] = __builtin_amdgcn_mfma_f32_16x16x32_bf16(pf0, vf0, o[dt], 0, 0, 0);
            o[dt] = __builtin_amdgcn_mfma_f32_16x16x32_bf16(pf1, vf1, o[dt], 0, 0, 0);
        }
        __syncthreads();   // protect Kls/Vt before next tile's staging
    }

    // ---- write O / l ----
    #pragma unroll
    for (int r = 0; r < 4; ++r) {
        const float inv = 1.0f / l_i[r];
        const size_t row = (size_t)b * T3_ + qt * 64 + w * 16 + quad * 4 + r;
        #pragma unroll
        for (int dt = 0; dt < 4; ++dt)
            Y[row * H_ + h * 64 + dt * 16 + l15] = f2bf(o[dt][r] * inv);
    }
}

// =====================================================================
// action head
// =====================================================================
__global__ __launch_bounds__(256) void head_kernel(
    const float* __restrict__ X, const float* __restrict__ W_pa,
    const float* __restrict__ b_pa, float* __restrict__ out)
{
    __shared__ float red[256];
    const int row = blockIdx.x;
    const int b = row / T_, t = row % T_;
    const float* x = X + ((size_t)b * T3_ + 3 * t + 1) * H_;
    const int tid = threadIdx.x;
    float s = 0.0f;
    #pragma unroll
    for (int u = 0; u < 4; ++u) {
        int col = tid + u * 256;
        s += x[col] * W_pa[col];
    }
    red[tid] = s; __syncthreads();
    for (int off = 128; off > 0; off >>= 1) {
        if (tid < off) red[tid] += red[tid + off];
        __syncthreads();
    }
    if (tid == 0) out[row] = red[0] + b_pa[0];
}

// =====================================================================
extern "C" void kernel_launch(void* const* d_in, const int* in_sizes, int n_in,
                              void* d_out, int out_size, void* d_ws, size_t ws_size,
                              hipStream_t stream)
{
    const float* states  = (const float*)d_in[0];
    const float* actions = (const float*)d_in[1];
    const float* rtgs    = (const float*)d_in[2];
    const float* amask   = (const float*)d_in[3];
    const float* smean   = (const float*)d_in[4];
    const float* sstd    = (const float*)d_in[5];
    const float* W_es    = (const float*)d_in[6];
    const float* b_es    = (const float*)d_in[7];
    const float* W_ea    = (const float*)d_in[8];
    const float* b_ea    = (const float*)d_in[9];
    const float* W_er    = (const float*)d_in[10];
    const float* b_er    = (const float*)d_in[11];
    const float* E_t     = (const float*)d_in[12];
    const float* W_ts    = (const float*)d_in[13];
    const float* b_ts    = (const float*)d_in[14];
    const float* W_ta    = (const float*)d_in[15];
    const float* b_ta    = (const float*)d_in[16];
    const float* W_tr    = (const float*)d_in[17];
    const float* b_tr    = (const float*)d_in[18];
    const float* eln_g   = (const float*)d_in[19];
    const float* eln_b   = (const float*)d_in[20];
    const float* ln1_g   = (const float*)d_in[21];
    const float* ln1_b   = (const float*)d_in[22];
    const float* ln2_g   = (const float*)d_in[23];
    const float* ln2_b   = (const float*)d_in[24];
    const float* Wq      = (const float*)d_in[25];
    const float* bq      = (const float*)d_in[26];
    const float* Wk      = (const float*)d_in[27];
    const float* bk      = (const float*)d_in[28];
    const float* Wv      = (const float*)d_in[29];
    const float* bv      = (const float*)d_in[30];
    const float* Wo      = (const float*)d_in[31];
    const float* bo      = (const float*)d_in[32];
    const float* W1      = (const float*)d_in[33];
    const float* b1      = (const float*)d_in[34];
    const float* W2      = (const float*)d_in[35];
    const float* b2      = (const float*)d_in[36];
    const float* W_pa    = (const float*)d_in[37];
    const float* b_pa    = (const float*)d_in[38];
    const int*   tsteps  = (const int*)d_in[39];
    float* out = (float*)d_out;

    // ---- workspace layout (bytes) ----
    char* base = (char*)d_ws;
    float* X    = (float*)base;                        // 25,165,824
    u16*   Hb   = (u16*)(base + 25165824);             // 12,582,912
    u16*   QKVb = (u16*)(base + 37748736);             // 37,748,736
    u16*   MIDb = (u16*)(base + 75497472);             // 50,331,648
    u16*   Wbuf = (u16*)(base + 125829120);            // 25,165,824 (end 150,994,944)

    float* bqkv = (float*)MIDb;
    u16* U_s = MIDb;
    u16* U_a = MIDb + (size_t)BT_ * KEP_;
    u16* U_r = MIDb + (size_t)2 * BT_ * KEP_;
    float* SE = (float*)QKVb;
    float* AE = SE + (size_t)BT_ * H_;
    float* RE = AE + (size_t)BT_ * H_;
    u16* Wtst = Wbuf;
    u16* Wtat = Wbuf + (size_t)H_ * KEP_;
    u16* Wtrt = Wbuf + (size_t)2 * H_ * KEP_;

    u16* WQKVt = Wbuf;                                 // [3072][1024]
    u16* Wot   = Wbuf + (size_t)3072 * 1024;           // [1024][1024]
    u16* W1t   = Wbuf + (size_t)4096 * 1024;           // [4096][1024]
    u16* W2t   = Wbuf + (size_t)8192 * 1024;           // [1024][4096]

    // ---- embedding ----
    embed_pre_kernel<<<BT_, 256, 0, stream>>>(
        states, actions, rtgs, smean, sstd, W_es, b_es, W_ea, b_ea,
        W_er, b_er, E_t, tsteps, U_s, U_a, U_r);

    dim3 gCvE(H_ / 32, KEP_ / 32);
    convT_kernel<<<gCvE, 256, 0, stream>>>(W_ts, Wtst, KE_, H_, KEP_);
    convT_kernel<<<gCvE, 256, 0, stream>>>(W_ta, Wtat, KE_, H_, KEP_);
    convT_kernel<<<gCvE, 256, 0, stream>>>(W_tr, Wtrt, KE_, H_, KEP_);

    dim3 gEmb(H_ / 128, BT_ / 64);                     // BM=64: 8 x 32
    mgemm<0, 64><<<gEmb, 256, 0, stream>>>(U_s, Wtst, b_ts, SE, nullptr, nullptr, H_, KEP_);
    mgemm<0, 64><<<gEmb, 256, 0, stream>>>(U_a, Wtat, b_ta, AE, nullptr, nullptr, H_, KEP_);
    mgemm<0, 64><<<gEmb, 256, 0, stream>>>(U_r, Wtrt, b_tr, RE, nullptr, nullptr, H_, KEP_);

    interleave_eln_kernel<<<ROWS_, 256, 0, stream>>>(RE, SE, AE, eln_g, eln_b, X);

    // ---- transformer layers ----
    dim3 gCv1(H_ / 32, H_ / 32);
    dim3 gCvM1(NI_ / 32, H_ / 32);
    dim3 gCvM2(H_ / 32, NI_ / 32);
    dim3 gQKV(3072 / 128, ROWS_ / 128);                // 24 x 48
    dim3 gO(H_ / 128, ROWS_ / 64);                     // BM=64: 8 x 96
    dim3 gM1(NI_ / 128, ROWS_ / 128);                  // 32 x 48
    dim3 gAttn(T3_ / 64, NH_, B_);                     // 12 x 16 x 8

    for (int l = 0; l < L_; ++l) {
        const size_t wOff = (size_t)l * H_ * H_;
        const size_t bOff = (size_t)l * H_;
        const size_t w1Off = (size_t)l * H_ * NI_;
        const size_t b1Off = (size_t)l * NI_;

        convT_kernel<<<gCv1, 256, 0, stream>>>(Wq + wOff, WQKVt, H_, H_, H_);
        convT_kernel<<<gCv1, 256, 0, stream>>>(Wk + wOff, WQKVt + (size_t)1024 * 1024, H_, H_, H_);
        convT_kernel<<<gCv1, 256, 0, stream>>>(Wv + wOff, WQKVt + (size_t)2048 * 1024, H_, H_, H_);
        convT_kernel<<<gCv1, 256, 0, stream>>>(Wo + wOff, Wot, H_, H_, H_);
        convT_kernel<<<gCvM1, 256, 0, stream>>>(W1 + w1Off, W1t, H_, NI_, H_);
        convT_kernel<<<gCvM2, 256, 0, stream>>>(W2 + w1Off, W2t, NI_, H_, NI_);
        pack_bias_kernel<<<12, 256, 0, stream>>>(bq + bOff, bk + bOff, bv + bOff, bqkv);

        ln_bf16_kernel<<<ROWS_, 256, 0, stream>>>(X, ln1_g + bOff, ln1_b + bOff, Hb);
        mgemm<2, 128><<<gQKV, 256, 0, stream>>>(Hb, WQKVt, bqkv, nullptr, QKVb, nullptr, 3072, H_);
        attn_kernel<<<gAttn, 256, 0, stream>>>(QKVb, amask, Hb);
        mgemm<1, 64><<<gO, 256, 0, stream>>>(Hb, Wot, bo + bOff, X, nullptr, X, H_, H_);
        ln_bf16_kernel<<<ROWS_, 256, 0, stream>>>(X, ln2_g + bOff, ln2_b + bOff, Hb);
        mgemm<3, 128><<<gM1, 256, 0, stream>>>(Hb, W1t, b1 + b1Off, nullptr, MIDb, nullptr, NI_, H_);
        mgemm<1, 64><<<gO, 256, 0, stream>>>(MIDb, W2t, b2 + bOff, X, nullptr, X, H_, NI_);
    }

    head_kernel<<<BT_, 256, 0, stream>>>(X, W_pa, b_pa, out);
}

// Round 4
// 3419.292 us; speedup vs baseline: 5.5688x; 1.0332x over previous
//
#include <hip/hip_runtime.h>
#include <math.h>

// ---- problem dims ----
#define B_    8
#define T_    256
#define S_    16
#define H_    1024
#define NH_   16
#define L_    6
#define NI_   4096
#define TIME_ 8
#define T3_   768           // 3*T
#define DH_   64            // H/NH
#define BT_   2048          // B*T
#define ROWS_ 6144          // B*T3
#define KE_   1032          // H + TIME
#define KEP_  1056          // KE padded to multiple of 32
#define NEGV  (-10000.0f)

typedef unsigned short u16;
typedef short bf16x8 __attribute__((ext_vector_type(8)));   // 8 bf16 in 4 VGPRs
typedef float f32x4 __attribute__((ext_vector_type(4)));

__device__ __forceinline__ float bf2f(u16 u) {
    union { unsigned int i; float f; } x; x.i = ((unsigned int)u) << 16; return x.f;
}
__device__ __forceinline__ u16 f2bf(float f) {
    union { float f; unsigned int i; } x; x.f = f;
    unsigned int r = x.i + 0x7FFFu + ((x.i >> 16) & 1u);   // RNE
    return (u16)(r >> 16);
}
// tanh-form GELU via hw exp: |err vs exact erf-gelu| < ~6e-4 (threshold 6.8e-2)
__device__ __forceinline__ float gelu_fast(float x) {
    float y = 0.7978845608028654f * (x + 0.044715f * x * x * x);
    float e = __expf(2.0f * y);
    float t = 1.0f - 2.0f / (e + 1.0f);
    return 0.5f * x * (1.0f + t);
}

// async global->LDS 16B: lds dest is wave-uniform base + lane*16 (m97 pattern)
__device__ __forceinline__ void gll16(const u16* g, u16* l) {
    __builtin_amdgcn_global_load_lds(
        (const __attribute__((address_space(1))) unsigned int*)g,
        (__attribute__((address_space(3))) unsigned int*)l,
        16, 0, 0);
}

// =====================================================================
// bf16 MFMA GEMM, double-buffered: C(M,N) = A(M,K) @ Bt(N,K)^T + bias.
// BMx128x32 tiles; one __syncthreads per K-iter; global_load_lds for
// tile i+1 issued right after the barrier (in flight during compute i).
// LDS granule layout: granule g = j*BM + row holds (row, k0+j*8 .. +7).
// EPI: 0 = bias -> f32, 1 = bias + residual(f32) -> f32,
//      2 = bias -> bf16, 3 = bias + gelu -> bf16
// =====================================================================
template <int EPI, int BM>
__global__ __launch_bounds__(256) void mgemm(
    const u16* __restrict__ A, const u16* __restrict__ Bt,
    const float* __restrict__ bias, float* __restrict__ outf,
    u16* __restrict__ outb, const float* __restrict__ res,
    int N, int K)
{
    constexpr int MT = (BM == 128) ? 4 : 2;     // 16-row m-tiles per wave
    __shared__ u16 Als[2][BM * 32];
    __shared__ u16 Bls[2][128 * 32];
    const int tid = threadIdx.x;
    const int bm = blockIdx.y * BM, bn = blockIdx.x * 128;

    const int lane = tid & 63;
    const int w = tid >> 6;                      // wave 0..3
    const int wr = (BM == 128) ? (w >> 1) : (w & 1);
    const int wc = (BM == 128) ? (w & 1) : (w >> 1);
    const int lrow = lane & 15;
    const int lk = lane >> 4;

    f32x4 acc[MT][4] = {};

    auto stage = [&](int buf, int kk) {
        if (BM == 128) {
            #pragma unroll
            for (int s = 0; s < 2; ++s) {
                const int gb = w * 64 + s * 256;          // wave-uniform granule base
                const int j = gb >> 7, m0 = gb & 127;
                gll16(A + (size_t)(bm + m0 + lane) * K + kk + j * 8, Als[buf] + gb * 8);
            }
        } else {
            gll16(A + (size_t)(bm + lane) * K + kk + w * 8, Als[buf] + w * 64 * 8);
        }
        #pragma unroll
        for (int s = 0; s < 2; ++s) {
            const int gb = w * 64 + s * 256;
            const int j = gb >> 7, m0 = gb & 127;
            gll16(Bt + (size_t)(bn + m0 + lane) * K + kk + j * 8, Bls[buf] + gb * 8);
        }
    };

    const int niter = K >> 5;
    stage(0, 0);
    for (int i = 0; i < niter; ++i) {
        __syncthreads();                          // loads into buf[i&1] landed;
                                                  // prior reads of buf[(i+1)&1] done
        if (i + 1 < niter) stage((i + 1) & 1, (i + 1) * 32);
        const bf16x8* Af = (const bf16x8*)Als[i & 1];
        const bf16x8* Bf = (const bf16x8*)Bls[i & 1];
        bf16x8 af[MT], bfr[4];
        #pragma unroll
        for (int tm = 0; tm < MT; ++tm)
            af[tm] = Af[lk * BM + wr * (MT * 16) + tm * 16 + lrow];
        #pragma unroll
        for (int tn = 0; tn < 4; ++tn)
            bfr[tn] = Bf[lk * 128 + wc * 64 + tn * 16 + lrow];
        #pragma unroll
        for (int tm = 0; tm < MT; ++tm)
            #pragma unroll
            for (int tn = 0; tn < 4; ++tn)
                acc[tm][tn] = __builtin_amdgcn_mfma_f32_16x16x32_bf16(
                    af[tm], bfr[tn], acc[tm][tn], 0, 0, 0);
    }

    // ---- epilogue: D row = quad*4+reg, col = lane&15 (per 16x16 tile) ----
    int cg[4]; float bv[4];
    #pragma unroll
    for (int tn = 0; tn < 4; ++tn) {
        cg[tn] = bn + wc * 64 + tn * 16 + lrow;
        bv[tn] = bias[cg[tn]];
    }
    #pragma unroll
    for (int tm = 0; tm < MT; ++tm) {
        const int rbase = bm + wr * (MT * 16) + tm * 16 + lk * 4;
        #pragma unroll
        for (int r = 0; r < 4; ++r) {
            const size_t rowoff = (size_t)(rbase + r) * N;
            #pragma unroll
            for (int tn = 0; tn < 4; ++tn) {
                float v = acc[tm][tn][r] + bv[tn];
                const size_t idx = rowoff + cg[tn];
                if (EPI == 0) outf[idx] = v;
                else if (EPI == 1) outf[idx] = v + res[idx];
                else if (EPI == 2) outb[idx] = f2bf(v);
                else { outb[idx] = f2bf(gelu_fast(v)); }
            }
        }
    }
}

// =====================================================================
// Weight transpose + fp32->bf16: W[K][N] fp32 -> Wt[N][Kpad] bf16
// =====================================================================
__global__ __launch_bounds__(256) void convT_kernel(
    const float* __restrict__ W, u16* __restrict__ Wt, int K, int N, int Kpad)
{
    __shared__ float tile[32][33];
    const int k0 = blockIdx.y * 32, n0 = blockIdx.x * 32;
    const int tx = threadIdx.x & 31, ty = threadIdx.x >> 5;   // 32 x 8
    #pragma unroll
    for (int i = 0; i < 32; i += 8) {
        int k = k0 + ty + i;
        tile[ty + i][tx] = (k < K) ? W[(size_t)k * N + n0 + tx] : 0.0f;
    }
    __syncthreads();
    #pragma unroll
    for (int i = 0; i < 32; i += 8) {
        int n = n0 + ty + i;
        Wt[(size_t)n * Kpad + k0 + tx] = f2bf(tile[tx][ty + i]);
    }
}

// fused per-layer transpose of Wq/Wk/Wv/Wo (grid.z = 0..3) + qkv bias pack
__global__ __launch_bounds__(256) void convT4_kernel(
    const float* __restrict__ Wq, const float* __restrict__ Wk,
    const float* __restrict__ Wv, const float* __restrict__ Wo,
    const float* __restrict__ bq, const float* __restrict__ bk,
    const float* __restrict__ bv,
    u16* __restrict__ WQKVt, u16* __restrict__ Wot, float* __restrict__ bqkv)
{
    const int z = blockIdx.z;
    const float* W = (z == 0) ? Wq : (z == 1) ? Wk : (z == 2) ? Wv : Wo;
    u16* Wt = (z == 3) ? Wot : WQKVt + (size_t)z * H_ * H_;
    __shared__ float tile[32][33];
    const int k0 = blockIdx.y * 32, n0 = blockIdx.x * 32;
    const int tx = threadIdx.x & 31, ty = threadIdx.x >> 5;
    #pragma unroll
    for (int i = 0; i < 32; i += 8)
        tile[ty + i][tx] = W[(size_t)(k0 + ty + i) * H_ + n0 + tx];
    __syncthreads();
    #pragma unroll
    for (int i = 0; i < 32; i += 8)
        Wt[(size_t)(n0 + ty + i) * H_ + k0 + tx] = f2bf(tile[tx][ty + i]);
    if (blockIdx.x == 0 && blockIdx.y == 0 && z < 3) {
        const float* bsrc = (z == 0) ? bq : (z == 1) ? bk : bv;
        #pragma unroll
        for (int u = 0; u < 4; ++u) {
            int i = threadIdx.x + u * 256;
            bqkv[z * H_ + i] = bsrc[i];
        }
    }
}

// =====================================================================
// embedding pre-stage
// =====================================================================
__global__ __launch_bounds__(256) void embed_pre_kernel(
    const float* __restrict__ states, const float* __restrict__ actions,
    const float* __restrict__ rtgs, const float* __restrict__ mean,
    const float* __restrict__ stdv, const float* __restrict__ W_es,
    const float* __restrict__ b_es, const float* __restrict__ W_ea,
    const float* __restrict__ b_ea, const float* __restrict__ W_er,
    const float* __restrict__ b_er, const float* __restrict__ E_t,
    const int* __restrict__ timesteps,
    u16* __restrict__ Us, u16* __restrict__ Ua, u16* __restrict__ Ur)
{
    const int bt  = blockIdx.x;
    const int tid = threadIdx.x;
    __shared__ float sn[S_];
    __shared__ float tev[TIME_];
    if (tid < S_) sn[tid] = (states[bt * S_ + tid] - mean[tid]) / (stdv[tid] + 1e-9f);
    if (tid < TIME_) {
        int ts = timesteps[bt];
        tev[tid] = E_t[ts * TIME_ + tid];
    }
    __syncthreads();
    const float av = actions[bt];
    const float rv = rtgs[bt];
    const size_t rowo = (size_t)bt * KEP_;
    #pragma unroll
    for (int u = 0; u < 4; ++u) {
        int n = tid + u * 256;
        float accs = b_es[n];
        #pragma unroll
        for (int i = 0; i < S_; ++i) accs += sn[i] * W_es[i * H_ + n];
        Us[rowo + n] = f2bf(accs);
        Ua[rowo + n] = f2bf(av * W_ea[n] + b_ea[n]);
        Ur[rowo + n] = f2bf(rv * W_er[n] + b_er[n]);
    }
    if (tid < TIME_) {
        u16 tv = f2bf(tev[tid]);
        Us[rowo + H_ + tid] = tv;
        Ua[rowo + H_ + tid] = tv;
        Ur[rowo + H_ + tid] = tv;
    }
    if (tid < KEP_ - KE_) {
        Us[rowo + KE_ + tid] = 0;
        Ua[rowo + KE_ + tid] = 0;
        Ur[rowo + KE_ + tid] = 0;
    }
}

// =====================================================================
// LayerNorm over rows of 1024
// =====================================================================
template <bool BF16OUT>
__device__ __forceinline__ void ln_body(const float* __restrict__ src,
                                        const float* __restrict__ g,
                                        const float* __restrict__ b,
                                        void* __restrict__ dst,
                                        float* red, int tid)
{
    float v[4];
    #pragma unroll
    for (int u = 0; u < 4; ++u) v[u] = src[tid + u * 256];
    float s = v[0] + v[1] + v[2] + v[3];
    red[tid] = s; __syncthreads();
    for (int off = 128; off > 0; off >>= 1) {
        if (tid < off) red[tid] += red[tid + off];
        __syncthreads();
    }
    const float mean = red[0] * (1.0f / H_);
    __syncthreads();
    float ss = 0.0f;
    #pragma unroll
    for (int u = 0; u < 4; ++u) { float d = v[u] - mean; ss += d * d; }
    red[tid] = ss; __syncthreads();
    for (int off = 128; off > 0; off >>= 1) {
        if (tid < off) red[tid] += red[tid + off];
        __syncthreads();
    }
    const float var = red[0] * (1.0f / H_);
    const float rs = rsqrtf(var + 1e-5f);
    #pragma unroll
    for (int u = 0; u < 4; ++u) {
        int col = tid + u * 256;
        float y = (v[u] - mean) * rs * g[col] + b[col];
        if (BF16OUT) ((u16*)dst)[col] = f2bf(y);
        else ((float*)dst)[col] = y;
    }
}

__global__ __launch_bounds__(256) void ln_bf16_kernel(
    const float* __restrict__ X, const float* __restrict__ g,
    const float* __restrict__ b, u16* __restrict__ Y)
{
    __shared__ float red[256];
    const size_t row = blockIdx.x;
    ln_body<true>(X + row * H_, g, b, Y + row * H_, red, threadIdx.x);
}

__global__ __launch_bounds__(256) void interleave_eln_kernel(
    const float* __restrict__ RE, const float* __restrict__ SE,
    const float* __restrict__ AE, const float* __restrict__ g,
    const float* __restrict__ b, float* __restrict__ X)
{
    __shared__ float red[256];
    const int row = blockIdx.x;
    const int bi = row / T3_;
    const int rem = row % T3_;
    const int t = rem / 3, slot = rem % 3;
    const float* src = (slot == 0 ? RE : (slot == 1 ? SE : AE)) + (size_t)(bi * T_ + t) * H_;
    ln_body<false>(src, g, b, X + (size_t)row * H_, red, threadIdx.x);
}

// =====================================================================
// MFMA flash attention. Block = 64 Q-rows x (head, batch); wave = 16 rows.
// =====================================================================
__global__ __launch_bounds__(256) void attn_kernel(
    const u16* __restrict__ QKV, const float* __restrict__ amask,
    u16* __restrict__ Y)
{
    const int qt = blockIdx.x;   // 0..11
    const int h  = blockIdx.y;   // 0..15
    const int b  = blockIdx.z;   // 0..7
    const int tid = threadIdx.x;
    const int lane = tid & 63, w = tid >> 6;
    const int l15 = lane & 15, quad = lane >> 4;

    __shared__ u16 Kls[64][72];      // row-major K tile (+8 pad)
    __shared__ u16 Vt[64][72];       // transposed V tile: Vt[dh][token]
    __shared__ u16 Pls[4][16][72];   // per-wave P tile
    __shared__ float padv[64];

    const u16* Qbase = QKV + (size_t)b * T3_ * 3072 + h * 64;
    const u16* Kbase = Qbase + 1024;
    const u16* Vbase = Qbase + 2048;

    bf16x8 qf[2];
    {
        const u16* qp = Qbase + (size_t)(qt * 64 + w * 16 + l15) * 3072 + quad * 8;
        qf[0] = *(const bf16x8*)qp;
        qf[1] = *(const bf16x8*)(qp + 32);
    }

    float m_i[4], l_i[4];
    f32x4 o[4] = {};
    #pragma unroll
    for (int r = 0; r < 4; ++r) { m_i[r] = -3.0e30f; l_i[r] = 0.0f; }

    const int qr0 = qt * 64 + w * 16 + quad * 4;

    for (int kt = 0; kt <= qt; ++kt) {
        #pragma unroll
        for (int s = 0; s < 2; ++s) {
            const int c = tid + s * 256;
            const int tok = c >> 3, cb = c & 7;
            const size_t go = (size_t)(kt * 64 + tok) * 3072 + cb * 8;
            *(uint4*)&Kls[tok][cb * 8] = *(const uint4*)(Kbase + go);
            uint4 vv = *(const uint4*)(Vbase + go);
            const u16* vs = (const u16*)&vv;
            #pragma unroll
            for (int j = 0; j < 8; ++j) Vt[cb * 8 + j][tok] = vs[j];
        }
        if (tid < 64)
            padv[tid] = (1.0f - amask[b * T_ + (kt * 64 + tid) / 3]) * NEGV;
        __syncthreads();

        f32x4 sacc[4];
        #pragma unroll
        for (int nt = 0; nt < 4; ++nt) {
            bf16x8 kf0 = *(const bf16x8*)&Kls[nt * 16 + l15][quad * 8];
            bf16x8 kf1 = *(const bf16x8*)&Kls[nt * 16 + l15][32 + quad * 8];
            f32x4 z = {};
            z = __builtin_amdgcn_mfma_f32_16x16x32_bf16(qf[0], kf0, z, 0, 0, 0);
            sacc[nt] = __builtin_amdgcn_mfma_f32_16x16x32_bf16(qf[1], kf1, z, 0, 0, 0);
        }

        float sv[4][4];
        float rmax[4] = {-3.0e30f, -3.0e30f, -3.0e30f, -3.0e30f};
        #pragma unroll
        for (int nt = 0; nt < 4; ++nt) {
            const int jc = kt * 64 + nt * 16 + l15;
            const float pv = padv[nt * 16 + l15];
            #pragma unroll
            for (int r = 0; r < 4; ++r) {
                float v = (jc <= qr0 + r) ? sacc[nt][r] * 0.125f : NEGV;
                v += pv;
                sv[nt][r] = v;
                rmax[r] = fmaxf(rmax[r], v);
            }
        }
        #pragma unroll
        for (int m = 1; m < 16; m <<= 1)
            #pragma unroll
            for (int r = 0; r < 4; ++r)
                rmax[r] = fmaxf(rmax[r], __shfl_xor(rmax[r], m, 64));
        float al[4], rsum[4];
        #pragma unroll
        for (int r = 0; r < 4; ++r) {
            const float mn = fmaxf(m_i[r], rmax[r]);
            al[r] = __expf(m_i[r] - mn);
            m_i[r] = mn;
            float sum = 0.0f;
            #pragma unroll
            for (int nt = 0; nt < 4; ++nt) {
                float p = __expf(sv[nt][r] - mn);
                sv[nt][r] = p; sum += p;
            }
            rsum[r] = sum;
        }
        #pragma unroll
        for (int m = 1; m < 16; m <<= 1)
            #pragma unroll
            for (int r = 0; r < 4; ++r)
                rsum[r] += __shfl_xor(rsum[r], m, 64);
        #pragma unroll
        for (int r = 0; r < 4; ++r)
            l_i[r] = l_i[r] * al[r] + rsum[r];

        #pragma unroll
        for (int nt = 0; nt < 4; ++nt)
            #pragma unroll
            for (int r = 0; r < 4; ++r)
                Pls[w][quad * 4 + r][nt * 16 + l15] = f2bf(sv[nt][r]);
        #pragma unroll
        for (int dt = 0; dt < 4; ++dt)
            #pragma unroll
            for (int r = 0; r < 4; ++r)
                o[dt][r] *= al[r];

        bf16x8 pf0 = *(const bf16x8*)&Pls[w][l15][quad * 8];
        bf16x8 pf1 = *(const bf16x8*)&Pls[w][l15][32 + quad * 8];
        #pragma unroll
        for (int dt = 0; dt < 4; ++dt) {
            bf16x8 vf0 = *(const bf16x8*)&Vt[dt * 16 + l15][quad * 8];
            bf16x8 vf1 = *(const bf16x8*)&Vt[dt * 16 + l15][32 + quad * 8];
            o[dt] = __builtin_amdgcn_mfma_f32_16x16x32_bf16(pf0, vf0, o[dt], 0, 0, 0);
            o[dt] = __builtin_amdgcn_mfma_f32_16x16x32_bf16(pf1, vf1, o[dt], 0, 0, 0);
        }
        __syncthreads();
    }

    #pragma unroll
    for (int r = 0; r < 4; ++r) {
        const float inv = 1.0f / l_i[r];
        const size_t row = (size_t)b * T3_ + qt * 64 + w * 16 + quad * 4 + r;
        #pragma unroll
        for (int dt = 0; dt < 4; ++dt)
            Y[row * H_ + h * 64 + dt * 16 + l15] = f2bf(o[dt][r] * inv);
    }
}

// =====================================================================
// action head
// =====================================================================
__global__ __launch_bounds__(256) void head_kernel(
    const float* __restrict__ X, const float* __restrict__ W_pa,
    const float* __restrict__ b_pa, float* __restrict__ out)
{
    __shared__ float red[256];
    const int row = blockIdx.x;
    const int b = row / T_, t = row % T_;
    const float* x = X + ((size_t)b * T3_ + 3 * t + 1) * H_;
    const int tid = threadIdx.x;
    float s = 0.0f;
    #pragma unroll
    for (int u = 0; u < 4; ++u) {
        int col = tid + u * 256;
        s += x[col] * W_pa[col];
    }
    red[tid] = s; __syncthreads();
    for (int off = 128; off > 0; off >>= 1) {
        if (tid < off) red[tid] += red[tid + off];
        __syncthreads();
    }
    if (tid == 0) out[row] = red[0] + b_pa[0];
}

// =====================================================================
extern "C" void kernel_launch(void* const* d_in, const int* in_sizes, int n_in,
                              void* d_out, int out_size, void* d_ws, size_t ws_size,
                              hipStream_t stream)
{
    const float* states  = (const float*)d_in[0];
    const float* actions = (const float*)d_in[1];
    const float* rtgs    = (const float*)d_in[2];
    const float* amask   = (const float*)d_in[3];
    const float* smean   = (const float*)d_in[4];
    const float* sstd    = (const float*)d_in[5];
    const float* W_es    = (const float*)d_in[6];
    const float* b_es    = (const float*)d_in[7];
    const float* W_ea    = (const float*)d_in[8];
    const float* b_ea    = (const float*)d_in[9];
    const float* W_er    = (const float*)d_in[10];
    const float* b_er    = (const float*)d_in[11];
    const float* E_t     = (const float*)d_in[12];
    const float* W_ts    = (const float*)d_in[13];
    const float* b_ts    = (const float*)d_in[14];
    const float* W_ta    = (const float*)d_in[15];
    const float* b_ta    = (const float*)d_in[16];
    const float* W_tr    = (const float*)d_in[17];
    const float* b_tr    = (const float*)d_in[18];
    const float* eln_g   = (const float*)d_in[19];
    const float* eln_b   = (const float*)d_in[20];
    const float* ln1_g   = (const float*)d_in[21];
    const float* ln1_b   = (const float*)d_in[22];
    const float* ln2_g   = (const float*)d_in[23];
    const float* ln2_b   = (const float*)d_in[24];
    const float* Wq      = (const float*)d_in[25];
    const float* bq      = (const float*)d_in[26];
    const float* Wk      = (const float*)d_in[27];
    const float* bk      = (const float*)d_in[28];
    const float* Wv      = (const float*)d_in[29];
    const float* bv      = (const float*)d_in[30];
    const float* Wo      = (const float*)d_in[31];
    const float* bo      = (const float*)d_in[32];
    const float* W1      = (const float*)d_in[33];
    const float* b1      = (const float*)d_in[34];
    const float* W2      = (const float*)d_in[35];
    const float* b2      = (const float*)d_in[36];
    const float* W_pa    = (const float*)d_in[37];
    const float* b_pa    = (const float*)d_in[38];
    const int*   tsteps  = (const int*)d_in[39];
    float* out = (float*)d_out;

    // ---- workspace layout (bytes) ----
    char* base = (char*)d_ws;
    float* X    = (float*)base;                        // 25,165,824
    u16*   Hb   = (u16*)(base + 25165824);             // 12,582,912
    u16*   QKVb = (u16*)(base + 37748736);             // 37,748,736
    u16*   MIDb = (u16*)(base + 75497472);             // 50,331,648
    u16*   Wbuf = (u16*)(base + 125829120);            // 25,165,824 (end 150,994,944)

    float* bqkv = (float*)MIDb;
    u16* U_s = MIDb;
    u16* U_a = MIDb + (size_t)BT_ * KEP_;
    u16* U_r = MIDb + (size_t)2 * BT_ * KEP_;
    float* SE = (float*)QKVb;
    float* AE = SE + (size_t)BT_ * H_;
    float* RE = AE + (size_t)BT_ * H_;
    u16* Wtst = Wbuf;
    u16* Wtat = Wbuf + (size_t)H_ * KEP_;
    u16* Wtrt = Wbuf + (size_t)2 * H_ * KEP_;

    u16* WQKVt = Wbuf;                                 // [3072][1024]
    u16* Wot   = Wbuf + (size_t)3072 * 1024;           // [1024][1024]
    u16* W1t   = Wbuf + (size_t)4096 * 1024;           // [4096][1024]
    u16* W2t   = Wbuf + (size_t)8192 * 1024;           // [1024][4096]

    // ---- embedding ----
    embed_pre_kernel<<<BT_, 256, 0, stream>>>(
        states, actions, rtgs, smean, sstd, W_es, b_es, W_ea, b_ea,
        W_er, b_er, E_t, tsteps, U_s, U_a, U_r);

    dim3 gCvE(H_ / 32, KEP_ / 32);
    convT_kernel<<<gCvE, 256, 0, stream>>>(W_ts, Wtst, KE_, H_, KEP_);
    convT_kernel<<<gCvE, 256, 0, stream>>>(W_ta, Wtat, KE_, H_, KEP_);
    convT_kernel<<<gCvE, 256, 0, stream>>>(W_tr, Wtrt, KE_, H_, KEP_);

    dim3 gEmb(H_ / 128, BT_ / 64);                     // BM=64: 8 x 32
    mgemm<0, 64><<<gEmb, 256, 0, stream>>>(U_s, Wtst, b_ts, SE, nullptr, nullptr, H_, KEP_);
    mgemm<0, 64><<<gEmb, 256, 0, stream>>>(U_a, Wtat, b_ta, AE, nullptr, nullptr, H_, KEP_);
    mgemm<0, 64><<<gEmb, 256, 0, stream>>>(U_r, Wtrt, b_tr, RE, nullptr, nullptr, H_, KEP_);

    interleave_eln_kernel<<<ROWS_, 256, 0, stream>>>(RE, SE, AE, eln_g, eln_b, X);

    // ---- transformer layers ----
    dim3 gCv4(H_ / 32, H_ / 32, 4);                    // fused QKV+O transpose
    dim3 gCvM1(NI_ / 32, H_ / 32);
    dim3 gCvM2(H_ / 32, NI_ / 32);
    dim3 gQKV(3072 / 128, ROWS_ / 128);                // 24 x 48
    dim3 gO(H_ / 128, ROWS_ / 64);                     // BM=64: 8 x 96
    dim3 gM1(NI_ / 128, ROWS_ / 128);                  // 32 x 48
    dim3 gAttn(T3_ / 64, NH_, B_);                     // 12 x 16 x 8

    for (int l = 0; l < L_; ++l) {
        const size_t wOff = (size_t)l * H_ * H_;
        const size_t bOff = (size_t)l * H_;
        const size_t w1Off = (size_t)l * H_ * NI_;
        const size_t b1Off = (size_t)l * NI_;

        convT4_kernel<<<gCv4, 256, 0, stream>>>(
            Wq + wOff, Wk + wOff, Wv + wOff, Wo + wOff,
            bq + bOff, bk + bOff, bv + bOff, WQKVt, Wot, bqkv);
        convT_kernel<<<gCvM1, 256, 0, stream>>>(W1 + w1Off, W1t, H_, NI_, H_);
        convT_kernel<<<gCvM2, 256, 0, stream>>>(W2 + w1Off, W2t, NI_, H_, NI_);

        ln_bf16_kernel<<<ROWS_, 256, 0, stream>>>(X, ln1_g + bOff, ln1_b + bOff, Hb);
        mgemm<2, 128><<<gQKV, 256, 0, stream>>>(Hb, WQKVt, bqkv, nullptr, QKVb, nullptr, 3072, H_);
        attn_kernel<<<gAttn, 256, 0, stream>>>(QKVb, amask, Hb);
        mgemm<1, 64><<<gO, 256, 0, stream>>>(Hb, Wot, bo + bOff, X, nullptr, X, H_, H_);
        ln_bf16_kernel<<<ROWS_, 256, 0, stream>>>(X, ln2_g + bOff, ln2_b + bOff, Hb);
        mgemm<3, 128><<<gM1, 256, 0, stream>>>(Hb, W1t, b1 + b1Off, nullptr, MIDb, nullptr, NI_, H_);
        mgemm<1, 64><<<gO, 256, 0, stream>>>(MIDb, W2t, b2 + bOff, X, nullptr, X, H_, NI_);
    }

    head_kernel<<<BT_, 256, 0, stream>>>(X, W_pa, b_pa, out);
}

// Round 5
// 3269.608 us; speedup vs baseline: 5.8237x; 1.0458x over previous
//
#include <hip/hip_runtime.h>
#include <math.h>

// ---- problem dims ----
#define B_    8
#define T_    256
#define S_    16
#define H_    1024
#define NH_   16
#define L_    6
#define NI_   4096
#define TIME_ 8
#define T3_   768           // 3*T
#define DH_   64            // H/NH
#define BT_   2048          // B*T
#define ROWS_ 6144          // B*T3
#define KE_   1032          // H + TIME
#define KEP_  1056          // KE padded to multiple of 32
#define NEGV  (-10000.0f)

typedef unsigned short u16;
typedef short bf16x8 __attribute__((ext_vector_type(8)));   // 8 bf16 in 4 VGPRs
typedef float f32x4 __attribute__((ext_vector_type(4)));

__device__ __forceinline__ float bf2f(u16 u) {
    union { unsigned int i; float f; } x; x.i = ((unsigned int)u) << 16; return x.f;
}
__device__ __forceinline__ u16 f2bf(float f) {
    union { float f; unsigned int i; } x; x.f = f;
    unsigned int r = x.i + 0x7FFFu + ((x.i >> 16) & 1u);   // RNE
    return (u16)(r >> 16);
}
// tanh-form GELU via hw exp: |err vs exact erf-gelu| < ~6e-4 (threshold 6.8e-2)
__device__ __forceinline__ float gelu_fast(float x) {
    float y = 0.7978845608028654f * (x + 0.044715f * x * x * x);
    float e = __expf(2.0f * y);
    float t = 1.0f - 2.0f / (e + 1.0f);
    return 0.5f * x * (1.0f + t);
}

// async global->LDS 16B: lds dest is wave-uniform base + lane*16 (m97 pattern)
__device__ __forceinline__ void gll16(const u16* g, u16* l) {
    __builtin_amdgcn_global_load_lds(
        (const __attribute__((address_space(1))) unsigned int*)g,
        (__attribute__((address_space(3))) unsigned int*)l,
        16, 0, 0);
}

// =====================================================================
// bf16 MFMA GEMM core, double-buffered, XCD-swizzled 1D grid.
// C(M,N) = A(M,K) @ Bt(N,K)^T + bias. BMx128x32 tiles.
// Swizzle: bids sharing an A row-panel are {base, base+8, ..} -> same XCD
// under round-robin dispatch, temporally adjacent -> A-panel L2 reuse.
// Requires (M/BM) % 8 == 0.
// EPI: 0 = bias -> f32, 1 = bias + residual(f32) -> f32,
//      2 = bias -> bf16, 3 = bias + gelu -> bf16
// =====================================================================
template <int EPI, int BM>
__device__ __forceinline__ void mgemm_core(
    const u16* __restrict__ A, const u16* __restrict__ Bt,
    const float* __restrict__ bias, float* __restrict__ outf,
    u16* __restrict__ outb, const float* __restrict__ res,
    int N, int K)
{
    constexpr int MT = (BM == 128) ? 4 : 2;     // 16-row m-tiles per wave
    __shared__ u16 Als[2][BM * 32];
    __shared__ u16 Bls[2][128 * 32];
    const int tid = threadIdx.x;

    // ---- swizzled block mapping ----
    const int nbx = N >> 7;
    const int bid = blockIdx.x;
    const int G = nbx << 3;
    const int grp = bid / G;
    const int g = bid - grp * G;
    const int bm = (grp * 8 + (g & 7)) * BM;
    const int bn = (g >> 3) * 128;

    const int lane = tid & 63;
    const int w = tid >> 6;                      // wave 0..3
    const int wr = (BM == 128) ? (w >> 1) : (w & 1);
    const int wc = (BM == 128) ? (w & 1) : (w >> 1);
    const int lrow = lane & 15;
    const int lk = lane >> 4;

    f32x4 acc[MT][4] = {};

    auto stage = [&](int buf, int kk) {
        if (BM == 128) {
            #pragma unroll
            for (int s = 0; s < 2; ++s) {
                const int gb = w * 64 + s * 256;          // wave-uniform granule base
                const int j = gb >> 7, m0 = gb & 127;
                gll16(A + (size_t)(bm + m0 + lane) * K + kk + j * 8, Als[buf] + gb * 8);
            }
        } else {
            gll16(A + (size_t)(bm + lane) * K + kk + w * 8, Als[buf] + w * 64 * 8);
        }
        #pragma unroll
        for (int s = 0; s < 2; ++s) {
            const int gb = w * 64 + s * 256;
            const int j = gb >> 7, m0 = gb & 127;
            gll16(Bt + (size_t)(bn + m0 + lane) * K + kk + j * 8, Bls[buf] + gb * 8);
        }
    };

    const int niter = K >> 5;
    stage(0, 0);
    for (int i = 0; i < niter; ++i) {
        __syncthreads();                          // loads into buf[i&1] landed
        if (i + 1 < niter) stage((i + 1) & 1, (i + 1) * 32);
        const bf16x8* Af = (const bf16x8*)Als[i & 1];
        const bf16x8* Bf = (const bf16x8*)Bls[i & 1];
        bf16x8 af[MT], bfr[4];
        #pragma unroll
        for (int tm = 0; tm < MT; ++tm)
            af[tm] = Af[lk * BM + wr * (MT * 16) + tm * 16 + lrow];
        #pragma unroll
        for (int tn = 0; tn < 4; ++tn)
            bfr[tn] = Bf[lk * 128 + wc * 64 + tn * 16 + lrow];
        #pragma unroll
        for (int tm = 0; tm < MT; ++tm)
            #pragma unroll
            for (int tn = 0; tn < 4; ++tn)
                acc[tm][tn] = __builtin_amdgcn_mfma_f32_16x16x32_bf16(
                    af[tm], bfr[tn], acc[tm][tn], 0, 0, 0);
    }

    // ---- epilogue: D row = quad*4+reg, col = lane&15 (per 16x16 tile) ----
    int cg[4]; float bv[4];
    #pragma unroll
    for (int tn = 0; tn < 4; ++tn) {
        cg[tn] = bn + wc * 64 + tn * 16 + lrow;
        bv[tn] = bias[cg[tn]];
    }
    #pragma unroll
    for (int tm = 0; tm < MT; ++tm) {
        const int rbase = bm + wr * (MT * 16) + tm * 16 + lk * 4;
        #pragma unroll
        for (int r = 0; r < 4; ++r) {
            const size_t rowoff = (size_t)(rbase + r) * N;
            #pragma unroll
            for (int tn = 0; tn < 4; ++tn) {
                float v = acc[tm][tn][r] + bv[tn];
                const size_t idx = rowoff + cg[tn];
                if (EPI == 0) outf[idx] = v;
                else if (EPI == 1) outf[idx] = v + res[idx];
                else if (EPI == 2) outb[idx] = f2bf(v);
                else { outb[idx] = f2bf(gelu_fast(v)); }
            }
        }
    }
}

template <int EPI, int BM>
__global__ __launch_bounds__(256) void mgemm(
    const u16* __restrict__ A, const u16* __restrict__ Bt,
    const float* __restrict__ bias, float* __restrict__ outf,
    u16* __restrict__ outb, const float* __restrict__ res,
    int N, int K)
{
    mgemm_core<EPI, BM>(A, Bt, bias, outf, outb, res, N, K);
}

// fused embed GEMMs: z = 0(s) / 1(a) / 2(r)
__global__ __launch_bounds__(256) void mgemm_embed(
    const u16* __restrict__ U, const u16* __restrict__ Wt,
    const float* __restrict__ b0, const float* __restrict__ b1,
    const float* __restrict__ b2, float* __restrict__ out)
{
    const int z = blockIdx.z;
    const float* bias = (z == 0) ? b0 : (z == 1) ? b1 : b2;
    mgemm_core<0, 64>(U + (size_t)z * BT_ * KEP_, Wt + (size_t)z * H_ * KEP_,
                      bias, out + (size_t)z * BT_ * H_, nullptr, nullptr,
                      H_, KEP_);
}

// =====================================================================
// Vectorized weight transpose + fp32->bf16: W[K][N] -> Wt[N][Kpad].
// 32(K) x 64(N) tile, float4 loads, ushort4 stores. Zero-fill k >= K.
// =====================================================================
__device__ __forceinline__ void convT_core(
    const float* __restrict__ W, u16* __restrict__ Wt, int K, int N, int Kpad)
{
    __shared__ float tile[32][65];
    const int k0 = blockIdx.y * 32, n0 = blockIdx.x * 64;
    const int tid = threadIdx.x;
    #pragma unroll
    for (int p = 0; p < 2; ++p) {
        const int kr = (tid >> 4) + p * 16;
        const int nc = (tid & 15) * 4;
        const int k = k0 + kr;
        float4 v = make_float4(0.f, 0.f, 0.f, 0.f);
        if (k < K) v = *(const float4*)(W + (size_t)k * N + n0 + nc);
        tile[kr][nc + 0] = v.x; tile[kr][nc + 1] = v.y;
        tile[kr][nc + 2] = v.z; tile[kr][nc + 3] = v.w;
    }
    __syncthreads();
    #pragma unroll
    for (int p = 0; p < 2; ++p) {
        const int idx = tid + p * 256;
        const int n = idx >> 3, kq = (idx & 7) * 4;
        ushort4 o;
        o.x = f2bf(tile[kq + 0][n]); o.y = f2bf(tile[kq + 1][n]);
        o.z = f2bf(tile[kq + 2][n]); o.w = f2bf(tile[kq + 3][n]);
        *(ushort4*)(Wt + (size_t)(n0 + n) * Kpad + k0 + kq) = o;
    }
}

__global__ __launch_bounds__(256) void convTv(
    const float* __restrict__ W, u16* __restrict__ Wt, int K, int N, int Kpad)
{
    convT_core(W, Wt, K, N, Kpad);
}

// embed weights: z = 0(ts)/1(ta)/2(tr), each [KE_][H_] -> [H_][KEP_]
__global__ __launch_bounds__(256) void convT_embed(
    const float* __restrict__ W0, const float* __restrict__ W1,
    const float* __restrict__ W2, u16* __restrict__ Wt)
{
    const int z = blockIdx.z;
    const float* W = (z == 0) ? W0 : (z == 1) ? W1 : W2;
    convT_core(W, Wt + (size_t)z * H_ * KEP_, KE_, H_, KEP_);
}

// per-layer QKV+O transpose (z=0..3) + qkv bias pack
__global__ __launch_bounds__(256) void convT4v(
    const float* __restrict__ Wq, const float* __restrict__ Wk,
    const float* __restrict__ Wv, const float* __restrict__ Wo,
    const float* __restrict__ bq, const float* __restrict__ bk,
    const float* __restrict__ bv,
    u16* __restrict__ WQKVt, u16* __restrict__ Wot, float* __restrict__ bqkv)
{
    const int z = blockIdx.z;
    const float* W = (z == 0) ? Wq : (z == 1) ? Wk : (z == 2) ? Wv : Wo;
    u16* Wt = (z == 3) ? Wot : WQKVt + (size_t)z * H_ * H_;
    convT_core(W, Wt, H_, H_, H_);
    if (blockIdx.x == 0 && blockIdx.y == 0 && z < 3) {
        const float* bsrc = (z == 0) ? bq : (z == 1) ? bk : bv;
        #pragma unroll
        for (int u = 0; u < 4; ++u) {
            int i = threadIdx.x + u * 256;
            bqkv[z * H_ + i] = bsrc[i];
        }
    }
}

// =====================================================================
// embedding pre-stage
// =====================================================================
__global__ __launch_bounds__(256) void embed_pre_kernel(
    const float* __restrict__ states, const float* __restrict__ actions,
    const float* __restrict__ rtgs, const float* __restrict__ mean,
    const float* __restrict__ stdv, const float* __restrict__ W_es,
    const float* __restrict__ b_es, const float* __restrict__ W_ea,
    const float* __restrict__ b_ea, const float* __restrict__ W_er,
    const float* __restrict__ b_er, const float* __restrict__ E_t,
    const int* __restrict__ timesteps,
    u16* __restrict__ Us, u16* __restrict__ Ua, u16* __restrict__ Ur)
{
    const int bt  = blockIdx.x;
    const int tid = threadIdx.x;
    __shared__ float sn[S_];
    __shared__ float tev[TIME_];
    if (tid < S_) sn[tid] = (states[bt * S_ + tid] - mean[tid]) / (stdv[tid] + 1e-9f);
    if (tid < TIME_) {
        int ts = timesteps[bt];
        tev[tid] = E_t[ts * TIME_ + tid];
    }
    __syncthreads();
    const float av = actions[bt];
    const float rv = rtgs[bt];
    const size_t rowo = (size_t)bt * KEP_;
    #pragma unroll
    for (int u = 0; u < 4; ++u) {
        int n = tid + u * 256;
        float accs = b_es[n];
        #pragma unroll
        for (int i = 0; i < S_; ++i) accs += sn[i] * W_es[i * H_ + n];
        Us[rowo + n] = f2bf(accs);
        Ua[rowo + n] = f2bf(av * W_ea[n] + b_ea[n]);
        Ur[rowo + n] = f2bf(rv * W_er[n] + b_er[n]);
    }
    if (tid < TIME_) {
        u16 tv = f2bf(tev[tid]);
        Us[rowo + H_ + tid] = tv;
        Ua[rowo + H_ + tid] = tv;
        Ur[rowo + H_ + tid] = tv;
    }
    if (tid < KEP_ - KE_) {
        Us[rowo + KE_ + tid] = 0;
        Ua[rowo + KE_ + tid] = 0;
        Ur[rowo + KE_ + tid] = 0;
    }
}

// =====================================================================
// LayerNorm over rows of 1024
// =====================================================================
template <bool BF16OUT>
__device__ __forceinline__ void ln_body(const float* __restrict__ src,
                                        const float* __restrict__ g,
                                        const float* __restrict__ b,
                                        void* __restrict__ dst,
                                        float* red, int tid)
{
    float v[4];
    #pragma unroll
    for (int u = 0; u < 4; ++u) v[u] = src[tid + u * 256];
    float s = v[0] + v[1] + v[2] + v[3];
    red[tid] = s; __syncthreads();
    for (int off = 128; off > 0; off >>= 1) {
        if (tid < off) red[tid] += red[tid + off];
        __syncthreads();
    }
    const float mean = red[0] * (1.0f / H_);
    __syncthreads();
    float ss = 0.0f;
    #pragma unroll
    for (int u = 0; u < 4; ++u) { float d = v[u] - mean; ss += d * d; }
    red[tid] = ss; __syncthreads();
    for (int off = 128; off > 0; off >>= 1) {
        if (tid < off) red[tid] += red[tid + off];
        __syncthreads();
    }
    const float var = red[0] * (1.0f / H_);
    const float rs = rsqrtf(var + 1e-5f);
    #pragma unroll
    for (int u = 0; u < 4; ++u) {
        int col = tid + u * 256;
        float y = (v[u] - mean) * rs * g[col] + b[col];
        if (BF16OUT) ((u16*)dst)[col] = f2bf(y);
        else ((float*)dst)[col] = y;
    }
}

__global__ __launch_bounds__(256) void ln_bf16_kernel(
    const float* __restrict__ X, const float* __restrict__ g,
    const float* __restrict__ b, u16* __restrict__ Y)
{
    __shared__ float red[256];
    const size_t row = blockIdx.x;
    ln_body<true>(X + row * H_, g, b, Y + row * H_, red, threadIdx.x);
}

__global__ __launch_bounds__(256) void interleave_eln_kernel(
    const float* __restrict__ RE, const float* __restrict__ SE,
    const float* __restrict__ AE, const float* __restrict__ g,
    const float* __restrict__ b, float* __restrict__ X)
{
    __shared__ float red[256];
    const int row = blockIdx.x;
    const int bi = row / T3_;
    const int rem = row % T3_;
    const int t = rem / 3, slot = rem % 3;
    const float* src = (slot == 0 ? RE : (slot == 1 ? SE : AE)) + (size_t)(bi * T_ + t) * H_;
    ln_body<false>(src, g, b, X + (size_t)row * H_, red, threadIdx.x);
}

// =====================================================================
// MFMA flash attention. Block = 64 Q-rows x (head, batch); wave = 16 rows.
// =====================================================================
__global__ __launch_bounds__(256) void attn_kernel(
    const u16* __restrict__ QKV, const float* __restrict__ amask,
    u16* __restrict__ Y)
{
    const int qt = blockIdx.x;   // 0..11
    const int h  = blockIdx.y;   // 0..15
    const int b  = blockIdx.z;   // 0..7
    const int tid = threadIdx.x;
    const int lane = tid & 63, w = tid >> 6;
    const int l15 = lane & 15, quad = lane >> 4;

    __shared__ u16 Kls[64][72];      // row-major K tile (+8 pad)
    __shared__ u16 Vt[64][72];       // transposed V tile: Vt[dh][token]
    __shared__ u16 Pls[4][16][72];   // per-wave P tile
    __shared__ float padv[64];

    const u16* Qbase = QKV + (size_t)b * T3_ * 3072 + h * 64;
    const u16* Kbase = Qbase + 1024;
    const u16* Vbase = Qbase + 2048;

    bf16x8 qf[2];
    {
        const u16* qp = Qbase + (size_t)(qt * 64 + w * 16 + l15) * 3072 + quad * 8;
        qf[0] = *(const bf16x8*)qp;
        qf[1] = *(const bf16x8*)(qp + 32);
    }

    float m_i[4], l_i[4];
    f32x4 o[4] = {};
    #pragma unroll
    for (int r = 0; r < 4; ++r) { m_i[r] = -3.0e30f; l_i[r] = 0.0f; }

    const int qr0 = qt * 64 + w * 16 + quad * 4;

    for (int kt = 0; kt <= qt; ++kt) {
        #pragma unroll
        for (int s = 0; s < 2; ++s) {
            const int c = tid + s * 256;
            const int tok = c >> 3, cb = c & 7;
            const size_t go = (size_t)(kt * 64 + tok) * 3072 + cb * 8;
            *(uint4*)&Kls[tok][cb * 8] = *(const uint4*)(Kbase + go);
            uint4 vv = *(const uint4*)(Vbase + go);
            const u16* vs = (const u16*)&vv;
            #pragma unroll
            for (int j = 0; j < 8; ++j) Vt[cb * 8 + j][tok] = vs[j];
        }
        if (tid < 64)
            padv[tid] = (1.0f - amask[b * T_ + (kt * 64 + tid) / 3]) * NEGV;
        __syncthreads();

        f32x4 sacc[4];
        #pragma unroll
        for (int nt = 0; nt < 4; ++nt) {
            bf16x8 kf0 = *(const bf16x8*)&Kls[nt * 16 + l15][quad * 8];
            bf16x8 kf1 = *(const bf16x8*)&Kls[nt * 16 + l15][32 + quad * 8];
            f32x4 z = {};
            z = __builtin_amdgcn_mfma_f32_16x16x32_bf16(qf[0], kf0, z, 0, 0, 0);
            sacc[nt] = __builtin_amdgcn_mfma_f32_16x16x32_bf16(qf[1], kf1, z, 0, 0, 0);
        }

        float sv[4][4];
        float rmax[4] = {-3.0e30f, -3.0e30f, -3.0e30f, -3.0e30f};
        #pragma unroll
        for (int nt = 0; nt < 4; ++nt) {
            const int jc = kt * 64 + nt * 16 + l15;
            const float pv = padv[nt * 16 + l15];
            #pragma unroll
            for (int r = 0; r < 4; ++r) {
                float v = (jc <= qr0 + r) ? sacc[nt][r] * 0.125f : NEGV;
                v += pv;
                sv[nt][r] = v;
                rmax[r] = fmaxf(rmax[r], v);
            }
        }
        #pragma unroll
        for (int m = 1; m < 16; m <<= 1)
            #pragma unroll
            for (int r = 0; r < 4; ++r)
                rmax[r] = fmaxf(rmax[r], __shfl_xor(rmax[r], m, 64));
        float al[4], rsum[4];
        #pragma unroll
        for (int r = 0; r < 4; ++r) {
            const float mn = fmaxf(m_i[r], rmax[r]);
            al[r] = __expf(m_i[r] - mn);
            m_i[r] = mn;
            float sum = 0.0f;
            #pragma unroll
            for (int nt = 0; nt < 4; ++nt) {
                float p = __expf(sv[nt][r] - mn);
                sv[nt][r] = p; sum += p;
            }
            rsum[r] = sum;
        }
        #pragma unroll
        for (int m = 1; m < 16; m <<= 1)
            #pragma unroll
            for (int r = 0; r < 4; ++r)
                rsum[r] += __shfl_xor(rsum[r], m, 64);
        #pragma unroll
        for (int r = 0; r < 4; ++r)
            l_i[r] = l_i[r] * al[r] + rsum[r];

        #pragma unroll
        for (int nt = 0; nt < 4; ++nt)
            #pragma unroll
            for (int r = 0; r < 4; ++r)
                Pls[w][quad * 4 + r][nt * 16 + l15] = f2bf(sv[nt][r]);
        #pragma unroll
        for (int dt = 0; dt < 4; ++dt)
            #pragma unroll
            for (int r = 0; r < 4; ++r)
                o[dt][r] *= al[r];

        bf16x8 pf0 = *(const bf16x8*)&Pls[w][l15][quad * 8];
        bf16x8 pf1 = *(const bf16x8*)&Pls[w][l15][32 + quad * 8];
        #pragma unroll
        for (int dt = 0; dt < 4; ++dt) {
            bf16x8 vf0 = *(const bf16x8*)&Vt[dt * 16 + l15][quad * 8];
            bf16x8 vf1 = *(const bf16x8*)&Vt[dt * 16 + l15][32 + quad * 8];
            o[dt] = __builtin_amdgcn_mfma_f32_16x16x32_bf16(pf0, vf0, o[dt], 0, 0, 0);
            o[dt] = __builtin_amdgcn_mfma_f32_16x16x32_bf16(pf1, vf1, o[dt], 0, 0, 0);
        }
        __syncthreads();
    }

    #pragma unroll
    for (int r = 0; r < 4; ++r) {
        const float inv = 1.0f / l_i[r];
        const size_t row = (size_t)b * T3_ + qt * 64 + w * 16 + quad * 4 + r;
        #pragma unroll
        for (int dt = 0; dt < 4; ++dt)
            Y[row * H_ + h * 64 + dt * 16 + l15] = f2bf(o[dt][r] * inv);
    }
}

// =====================================================================
// action head
// =====================================================================
__global__ __launch_bounds__(256) void head_kernel(
    const float* __restrict__ X, const float* __restrict__ W_pa,
    const float* __restrict__ b_pa, float* __restrict__ out)
{
    __shared__ float red[256];
    const int row = blockIdx.x;
    const int b = row / T_, t = row % T_;
    const float* x = X + ((size_t)b * T3_ + 3 * t + 1) * H_;
    const int tid = threadIdx.x;
    float s = 0.0f;
    #pragma unroll
    for (int u = 0; u < 4; ++u) {
        int col = tid + u * 256;
        s += x[col] * W_pa[col];
    }
    red[tid] = s; __syncthreads();
    for (int off = 128; off > 0; off >>= 1) {
        if (tid < off) red[tid] += red[tid + off];
        __syncthreads();
    }
    if (tid == 0) out[row] = red[0] + b_pa[0];
}

// =====================================================================
extern "C" void kernel_launch(void* const* d_in, const int* in_sizes, int n_in,
                              void* d_out, int out_size, void* d_ws, size_t ws_size,
                              hipStream_t stream)
{
    const float* states  = (const float*)d_in[0];
    const float* actions = (const float*)d_in[1];
    const float* rtgs    = (const float*)d_in[2];
    const float* amask   = (const float*)d_in[3];
    const float* smean   = (const float*)d_in[4];
    const float* sstd    = (const float*)d_in[5];
    const float* W_es    = (const float*)d_in[6];
    const float* b_es    = (const float*)d_in[7];
    const float* W_ea    = (const float*)d_in[8];
    const float* b_ea    = (const float*)d_in[9];
    const float* W_er    = (const float*)d_in[10];
    const float* b_er    = (const float*)d_in[11];
    const float* E_t     = (const float*)d_in[12];
    const float* W_ts    = (const float*)d_in[13];
    const float* b_ts    = (const float*)d_in[14];
    const float* W_ta    = (const float*)d_in[15];
    const float* b_ta    = (const float*)d_in[16];
    const float* W_tr    = (const float*)d_in[17];
    const float* b_tr    = (const float*)d_in[18];
    const float* eln_g   = (const float*)d_in[19];
    const float* eln_b   = (const float*)d_in[20];
    const float* ln1_g   = (const float*)d_in[21];
    const float* ln1_b   = (const float*)d_in[22];
    const float* ln2_g   = (const float*)d_in[23];
    const float* ln2_b   = (const float*)d_in[24];
    const float* Wq      = (const float*)d_in[25];
    const float* bq      = (const float*)d_in[26];
    const float* Wk      = (const float*)d_in[27];
    const float* bk      = (const float*)d_in[28];
    const float* Wv      = (const float*)d_in[29];
    const float* bv      = (const float*)d_in[30];
    const float* Wo      = (const float*)d_in[31];
    const float* bo      = (const float*)d_in[32];
    const float* W1      = (const float*)d_in[33];
    const float* b1      = (const float*)d_in[34];
    const float* W2      = (const float*)d_in[35];
    const float* b2      = (const float*)d_in[36];
    const float* W_pa    = (const float*)d_in[37];
    const float* b_pa    = (const float*)d_in[38];
    const int*   tsteps  = (const int*)d_in[39];
    float* out = (float*)d_out;

    // ---- workspace layout (bytes) ----
    char* base = (char*)d_ws;
    float* X    = (float*)base;                        // 25,165,824
    u16*   Hb   = (u16*)(base + 25165824);             // 12,582,912
    u16*   QKVb = (u16*)(base + 37748736);             // 37,748,736
    u16*   MIDb = (u16*)(base + 75497472);             // 50,331,648
    u16*   Wbuf = (u16*)(base + 125829120);            // 25,165,824 (end 150,994,944)

    float* bqkv = (float*)MIDb;
    u16* U_s = MIDb;
    u16* U_a = MIDb + (size_t)BT_ * KEP_;
    u16* U_r = MIDb + (size_t)2 * BT_ * KEP_;
    float* SE = (float*)QKVb;                          // SE, AE, RE consecutive
    float* AE = SE + (size_t)BT_ * H_;
    float* RE = AE + (size_t)BT_ * H_;
    u16* Wemb = Wbuf;                                  // 3 x [H_][KEP_]

    u16* WQKVt = Wbuf;                                 // [3072][1024]
    u16* Wot   = Wbuf + (size_t)3072 * 1024;           // [1024][1024]
    u16* W1t   = Wbuf + (size_t)4096 * 1024;           // [4096][1024]
    u16* W2t   = Wbuf + (size_t)8192 * 1024;           // [1024][4096]

    // ---- embedding ----
    embed_pre_kernel<<<BT_, 256, 0, stream>>>(
        states, actions, rtgs, smean, sstd, W_es, b_es, W_ea, b_ea,
        W_er, b_er, E_t, tsteps, U_s, U_a, U_r);

    dim3 gCvE(H_ / 64, KEP_ / 32, 3);                  // 16 x 33 x 3
    convT_embed<<<gCvE, 256, 0, stream>>>(W_ts, W_ta, W_tr, Wemb);

    dim3 gEmb((H_ / 128) * (BT_ / 64), 1, 3);          // 256 x 1 x 3
    mgemm_embed<<<gEmb, 256, 0, stream>>>(U_s, Wemb, b_ts, b_ta, b_tr, SE);

    interleave_eln_kernel<<<ROWS_, 256, 0, stream>>>(RE, SE, AE, eln_g, eln_b, X);

    // ---- transformer layers ----
    dim3 gCv4(H_ / 64, H_ / 32, 4);                    // QKV+O transpose
    dim3 gCvM1(NI_ / 64, H_ / 32);                     // W1
    dim3 gCvM2(H_ / 64, NI_ / 32);                     // W2
    const int gQKV = (3072 / 128) * (ROWS_ / 128);     // 1152
    const int gO   = (H_ / 128) * (ROWS_ / 64);        // 768
    const int gM1  = (NI_ / 128) * (ROWS_ / 128);      // 1536
    dim3 gAttn(T3_ / 64, NH_, B_);                     // 12 x 16 x 8

    for (int l = 0; l < L_; ++l) {
        const size_t wOff = (size_t)l * H_ * H_;
        const size_t bOff = (size_t)l * H_;
        const size_t w1Off = (size_t)l * H_ * NI_;
        const size_t b1Off = (size_t)l * NI_;

        convT4v<<<gCv4, 256, 0, stream>>>(
            Wq + wOff, Wk + wOff, Wv + wOff, Wo + wOff,
            bq + bOff, bk + bOff, bv + bOff, WQKVt, Wot, bqkv);
        convTv<<<gCvM1, 256, 0, stream>>>(W1 + w1Off, W1t, H_, NI_, H_);
        convTv<<<gCvM2, 256, 0, stream>>>(W2 + w1Off, W2t, NI_, H_, NI_);

        ln_bf16_kernel<<<ROWS_, 256, 0, stream>>>(X, ln1_g + bOff, ln1_b + bOff, Hb);
        mgemm<2, 128><<<gQKV, 256, 0, stream>>>(Hb, WQKVt, bqkv, nullptr, QKVb, nullptr, 3072, H_);
        attn_kernel<<<gAttn, 256, 0, stream>>>(QKVb, amask, Hb);
        mgemm<1, 64><<<gO, 256, 0, stream>>>(Hb, Wot, bo + bOff, X, nullptr, X, H_, H_);
        ln_bf16_kernel<<<ROWS_, 256, 0, stream>>>(X, ln2_g + bOff, ln2_b + bOff, Hb);
        mgemm<3, 128><<<gM1, 256, 0, stream>>>(Hb, W1t, b1 + b1Off, nullptr, MIDb, nullptr, NI_, H_);
        mgemm<1, 64><<<gO, 256, 0, stream>>>(MIDb, W2t, b2 + bOff, X, nullptr, X, H_, NI_);
    }

    head_kernel<<<BT_, 256, 0, stream>>>(X, W_pa, b_pa, out);
}